// Round 3
// baseline (588.840 us; speedup 1.0000x reference)
//
#include <hip/hip_runtime.h>
#include <hip/hip_bf16.h>
#include <math.h>

// Problem constants
#define BB 16
#define HH 512
#define LL 4096
#define NFFT 8192
#define LAM 0.001f

typedef __attribute__((ext_vector_type(8))) short short8;
typedef __attribute__((ext_vector_type(4))) float floatx4;

__device__ __forceinline__ void cmul(float ar, float ai, float br, float bi,
                                     float& cr, float& ci) {
  cr = ar * br - ai * bi;
  ci = ar * bi + ai * br;
}

// W16^e = exp(-2*pi*i*e/16), e = j*m for j,m in [0,4)
constexpr float W16C[10] = {1.f, 0.92387953f, 0.70710678f, 0.38268343f, 0.f,
                            -0.38268343f, -0.70710678f, -0.92387953f, -1.f, -0.92387953f};
constexpr float W16S[10] = {0.f, -0.38268343f, -0.70710678f, -0.92387953f, -1.f,
                            -0.92387953f, -0.70710678f, -0.38268343f, 0.f, 0.38268343f};
// W32^j = exp(-2*pi*i*j/32), j in [0,16)
constexpr float W32C[16] = {1.f, 0.98078528f, 0.92387953f, 0.83146961f, 0.70710678f,
                            0.55557023f, 0.38268343f, 0.19509032f, 0.f, -0.19509032f,
                            -0.38268343f, -0.55557023f, -0.70710678f, -0.83146961f,
                            -0.92387953f, -0.98078528f};
constexpr float W32S[16] = {0.f, -0.19509032f, -0.38268343f, -0.55557023f, -0.70710678f,
                            -0.83146961f, -0.92387953f, -0.98078528f, -1.f, -0.98078528f,
                            -0.92387953f, -0.83146961f, -0.70710678f, -0.55557023f,
                            -0.38268343f, -0.19509032f};

// ---- 16-point DIF FFT, natural-order in/out, in registers ----
__device__ __forceinline__ void fft16_f(float* xr, float* xi) {
  float yr[16], yi[16];
#pragma unroll
  for (int j = 0; j < 4; ++j) {
    float t0r = xr[j] + xr[j + 8],      t0i = xi[j] + xi[j + 8];
    float t1r = xr[j] - xr[j + 8],      t1i = xi[j] - xi[j + 8];
    float t2r = xr[j + 4] + xr[j + 12], t2i = xi[j + 4] + xi[j + 12];
    float t3r = xr[j + 4] - xr[j + 12], t3i = xi[j + 4] - xi[j + 12];
    float o0r = t0r + t2r, o0i = t0i + t2i;
    float o1r = t1r + t3i, o1i = t1i - t3r;   // t1 - i t3
    float o2r = t0r - t2r, o2i = t0i - t2i;
    float o3r = t1r - t3i, o3i = t1i + t3r;   // t1 + i t3
    yr[j] = o0r; yi[j] = o0i;
    if (j == 0) {
      yr[4] = o1r; yi[4] = o1i; yr[8] = o2r; yi[8] = o2i; yr[12] = o3r; yi[12] = o3i;
    } else {
      cmul(o1r, o1i, W16C[j], W16S[j], yr[j + 4], yi[j + 4]);
      cmul(o2r, o2i, W16C[2 * j], W16S[2 * j], yr[j + 8], yi[j + 8]);
      cmul(o3r, o3i, W16C[3 * j], W16S[3 * j], yr[j + 12], yi[j + 12]);
    }
  }
#pragma unroll
  for (int m = 0; m < 4; ++m) {
    float t0r = yr[4 * m] + yr[4 * m + 2],     t0i = yi[4 * m] + yi[4 * m + 2];
    float t1r = yr[4 * m] - yr[4 * m + 2],     t1i = yi[4 * m] - yi[4 * m + 2];
    float t2r = yr[4 * m + 1] + yr[4 * m + 3], t2i = yi[4 * m + 1] + yi[4 * m + 3];
    float t3r = yr[4 * m + 1] - yr[4 * m + 3], t3i = yi[4 * m + 1] - yi[4 * m + 3];
    xr[m] = t0r + t2r;       xi[m] = t0i + t2i;
    xr[m + 4] = t1r + t3i;   xi[m + 4] = t1i - t3r;
    xr[m + 8] = t0r - t2r;   xi[m + 8] = t0i - t2i;
    xr[m + 12] = t1r - t3i;  xi[m + 12] = t1i + t3r;
  }
}

// ---- inverse (unnormalized x16), natural-order in/out ----
__device__ __forceinline__ void ifft16_f(float* xr, float* xi) {
  float yr[16], yi[16];
#pragma unroll
  for (int m = 0; m < 4; ++m) {
    float t0r = xr[m] + xr[m + 8],      t0i = xi[m] + xi[m + 8];
    float t1r = xr[m] - xr[m + 8],      t1i = xi[m] - xi[m + 8];
    float t2r = xr[m + 4] + xr[m + 12], t2i = xi[m + 4] + xi[m + 12];
    float t3r = xr[m + 4] - xr[m + 12], t3i = xi[m + 4] - xi[m + 12];
    yr[4 * m] = t0r + t2r;     yi[4 * m] = t0i + t2i;
    yr[4 * m + 1] = t1r - t3i; yi[4 * m + 1] = t1i + t3r;  // t1 + i t3
    yr[4 * m + 2] = t0r - t2r; yi[4 * m + 2] = t0i - t2i;
    yr[4 * m + 3] = t1r + t3i; yi[4 * m + 3] = t1i - t3r;  // t1 - i t3
  }
#pragma unroll
  for (int j = 0; j < 4; ++j) {
    float v0r = yr[j], v0i = yi[j];
    float v1r, v1i, v2r, v2i, v3r, v3i;
    if (j == 0) {
      v1r = yr[4]; v1i = yi[4]; v2r = yr[8]; v2i = yi[8]; v3r = yr[12]; v3i = yi[12];
    } else {
      cmul(yr[j + 4], yi[j + 4], W16C[j], -W16S[j], v1r, v1i);
      cmul(yr[j + 8], yi[j + 8], W16C[2 * j], -W16S[2 * j], v2r, v2i);
      cmul(yr[j + 12], yi[j + 12], W16C[3 * j], -W16S[3 * j], v3r, v3i);
    }
    float t0r = v0r + v2r, t0i = v0i + v2i;
    float t1r = v0r - v2r, t1i = v0i - v2i;
    float t2r = v1r + v3r, t2i = v1i + v3i;
    float t3r = v1r - v3r, t3i = v1i - v3i;
    xr[j] = t0r + t2r;       xi[j] = t0i + t2i;
    xr[j + 4] = t1r - t3i;   xi[j + 4] = t1i + t3r;
    xr[j + 8] = t0r - t2r;   xi[j + 8] = t0i - t2i;
    xr[j + 12] = t1r + t3i;  xi[j + 12] = t1i - t3r;
  }
}

__device__ __forceinline__ float gelu_exact(float y) {
  return 0.5f * y * (1.f + erff(y * 0.70710678118654752f));
}

// -------- pass -1: twiddle tables ------------------------------------------
// tw1[m2][j] = (cos,sin of -2pi*j*(2m2)/8192, cos,sin of -2pi*j*(2m2+1)/8192)
//   m2 in [0,8), j in [0,512)  -> 64 KB, coalesced float4 per (m2, lane=j)
// tw2[m2][jj] = same with /512, jj in [0,32)  -> 4 KB
// Replaces the per-thread twtree (32 live VGPRs of wc/ws) with streamed loads.
__global__ __launch_bounds__(512) void twgen_kernel(float4* __restrict__ tw1,
                                                    float4* __restrict__ tw2) {
  const int j = threadIdx.x;
  const int m2 = blockIdx.x;  // 0..7
  float s0, c0, s1, c1;
  const float a1 = -6.283185307179586f / 8192.f;
  sincosf(a1 * (float)(j * (2 * m2)), &s0, &c0);
  sincosf(a1 * (float)(j * (2 * m2 + 1)), &s1, &c1);
  tw1[m2 * 512 + j] = make_float4(c0, s0, c1, s1);
  if (j < 32) {
    const float a2 = -6.283185307179586f / 512.f;
    sincosf(a2 * (float)(j * (2 * m2)), &s0, &c0);
    sincosf(a2 * (float)(j * (2 * m2 + 1)), &s1, &c1);
    tw2[m2 * 32 + j] = make_float4(c0, s0, c1, s1);
  }
}

// -------- pass 0: Wout fp32 -> bf16 ----------------------------------------
__global__ void wconv_kernel(const float* __restrict__ W,
                             __hip_bfloat16* __restrict__ Wb) {
  int i = blockIdx.x * 256 + threadIdx.x;
  Wb[i] = __float2bfloat16(W[i]);
}

// -------- pass 1: squash kernel + scrambled spectrum (x 1/N) + D-fold ------
// Skip term folded into the spectrum: conv(u,k) + D*u = IFFT(U*(Kf + D/N)),
// since adding c to EVERY bin adds c*N*delta_0 to the time-domain kernel.
// Scramble-proof (constant is order-independent).
__global__ __launch_bounds__(512)
void kf_kernel(const float* __restrict__ kern, const float* __restrict__ D,
               float* __restrict__ Kf, const float4* __restrict__ tw1,
               const float4* __restrict__ tw2) {
  __shared__ __align__(16) float sre[NFFT];
  __shared__ __align__(16) float sim[NFFT];
  const int t = threadIdx.x;
  const int h = blockIdx.x;
  const float* kr = kern + (size_t)h * LL;

  // P1: radix-16, q=512
  {
    const int j = t;
    float xr[16], xi[16];
#pragma unroll
    for (int r = 0; r < 8; ++r) {
      float kv = kr[j + 512 * r];
      float a = fabsf(kv) - LAM;
      float sq = (a > 0.f) ? ((kv > 0.f) ? a : -a) : 0.f;
      xr[r] = sq * (1.0f / (float)NFFT);
      xi[r] = 0.f;
    }
#pragma unroll
    for (int r = 8; r < 16; ++r) { xr[r] = 0.f; xi[r] = 0.f; }
    fft16_f(xr, xi);
    const int jx = j ^ (((j >> 5) & 7) << 2);
#pragma unroll
    for (int m2 = 0; m2 < 8; ++m2) {
      float4 w = tw1[m2 * 512 + j];
      float tr, ti;
      cmul(xr[2 * m2], xi[2 * m2], w.x, w.y, tr, ti);
      sre[jx + 512 * (2 * m2)] = tr; sim[jx + 512 * (2 * m2)] = ti;
      cmul(xr[2 * m2 + 1], xi[2 * m2 + 1], w.z, w.w, tr, ti);
      sre[jx + 512 * (2 * m2 + 1)] = tr; sim[jx + 512 * (2 * m2 + 1)] = ti;
    }
  }
  __syncthreads();

  // P2: radix-16, q=32
  {
    const int jj = t & 31, gg = t >> 5;
    const int base = gg * 512 + jj;
    float xr[16], xi[16];
#pragma unroll
    for (int m = 0; m < 16; ++m) {
      const int a = (base + 32 * m) ^ ((m & 7) << 2);
      xr[m] = sre[a]; xi[m] = sim[a];
    }
    fft16_f(xr, xi);
#pragma unroll
    for (int m2 = 0; m2 < 8; ++m2) {
      float4 w = tw2[m2 * 32 + jj];
      float tr, ti;
      int a0 = (base + 32 * (2 * m2)) ^ (((2 * m2) & 7) << 2);
      cmul(xr[2 * m2], xi[2 * m2], w.x, w.y, tr, ti);
      sre[a0] = tr; sim[a0] = ti;
      int a1 = (base + 32 * (2 * m2 + 1)) ^ (((2 * m2 + 1) & 7) << 2);
      cmul(xr[2 * m2 + 1], xi[2 * m2 + 1], w.z, w.w, tr, ti);
      sre[a1] = tr; sim[a1] = ti;
    }
  }
  __syncthreads();

  // P3: block k=t>>1 of 32 contiguous; radix-2 split (par=t&1) + DFT16
  {
    const int k = t >> 1, par = t & 1;
    const int kx = k & 7;
    const float sgn = par ? -1.f : 1.f;
    float xr[16], xi[16];
#pragma unroll
    for (int c = 0; c < 4; ++c) {
      float4 lr = ((const float4*)sre)[8 * k + (c ^ kx)];
      float4 hr = ((const float4*)sre)[8 * k + ((c + 4) ^ kx)];
      float4 li = ((const float4*)sim)[8 * k + (c ^ kx)];
      float4 hi4 = ((const float4*)sim)[8 * k + ((c + 4) ^ kx)];
      float vr[4] = {lr.x + sgn * hr.x, lr.y + sgn * hr.y, lr.z + sgn * hr.z, lr.w + sgn * hr.w};
      float vi[4] = {li.x + sgn * hi4.x, li.y + sgn * hi4.y, li.z + sgn * hi4.z, li.w + sgn * hi4.w};
#pragma unroll
      for (int e = 0; e < 4; ++e) {
        const int j = 4 * c + e;
        const float twr = par ? W32C[j] : 1.f;
        const float tws = par ? W32S[j] : 0.f;
        cmul(vr[e], vi[e], twr, tws, xr[j], xi[j]);
      }
    }
    fft16_f(xr, xi);
    const float dsc = D[h] * (1.0f / (float)NFFT);  // skip-term fold
    float4* out4 = (float4*)(Kf + (size_t)h * NFFT * 2) + 8 * t;
#pragma unroll
    for (int c = 0; c < 8; ++c)
      out4[c] = make_float4(xr[2 * c] + dsc, xi[2 * c], xr[2 * c + 1] + dsc, xi[2 * c + 1]);
  }
}

// -------- pass 2: FFT conv (h, batch-pair) + GELU -> g bf16 ----------------
// grid = (HH, BB/2): linear id = p*512 + h, so id%8 = h%8 -> all 8 batch-pair
// blocks of one h land on the SAME XCD and reuse its Kf row from that L2.
// Skip term is pre-folded into Kf, so no u stash / D load here.
__global__ __launch_bounds__(512)
void fftconv_kernel(
    const float* __restrict__ u, const float* __restrict__ Kf,
    __hip_bfloat16* __restrict__ g, const float4* __restrict__ tw1,
    const float4* __restrict__ tw2) {
  __shared__ __align__(16) float sre[NFFT];
  __shared__ __align__(16) float sim[NFFT];
  const int t = threadIdx.x;
  const int h = blockIdx.x;   // 0..511
  const int p = blockIdx.y;   // batch pair 0..7
  const int b0 = 2 * p, b1 = 2 * p + 1;
  const float* u0 = u + ((size_t)(b0 * HH + h)) * LL;
  const float* u1 = u + ((size_t)(b1 * HH + h)) * LL;

  const int jx = t ^ (((t >> 5) & 7) << 2);

  // ---- P1: radix-16, q=512, z = u0 + i*u1 ----
  {
    const int j = t;
    float xr[16], xi[16];
#pragma unroll
    for (int r = 0; r < 8; ++r) {
      xr[r] = u0[j + 512 * r];
      xi[r] = u1[j + 512 * r];
    }
#pragma unroll
    for (int r = 8; r < 16; ++r) { xr[r] = 0.f; xi[r] = 0.f; }
    fft16_f(xr, xi);
#pragma unroll
    for (int m2 = 0; m2 < 8; ++m2) {
      float4 w = tw1[m2 * 512 + j];
      float tr, ti;
      cmul(xr[2 * m2], xi[2 * m2], w.x, w.y, tr, ti);
      sre[jx + 512 * (2 * m2)] = tr; sim[jx + 512 * (2 * m2)] = ti;
      cmul(xr[2 * m2 + 1], xi[2 * m2 + 1], w.z, w.w, tr, ti);
      sre[jx + 512 * (2 * m2 + 1)] = tr; sim[jx + 512 * (2 * m2 + 1)] = ti;
    }
  }
  __syncthreads();

  // ---- P2: radix-16, q=32 ----
  {
    const int jj = t & 31, gg = t >> 5;
    const int base = gg * 512 + jj;
    float xr[16], xi[16];
#pragma unroll
    for (int m = 0; m < 16; ++m) {
      const int a = (base + 32 * m) ^ ((m & 7) << 2);
      xr[m] = sre[a]; xi[m] = sim[a];
    }
    fft16_f(xr, xi);
#pragma unroll
    for (int m2 = 0; m2 < 8; ++m2) {
      float4 w = tw2[m2 * 32 + jj];
      float tr, ti;
      int a0 = (base + 32 * (2 * m2)) ^ (((2 * m2) & 7) << 2);
      cmul(xr[2 * m2], xi[2 * m2], w.x, w.y, tr, ti);
      sre[a0] = tr; sim[a0] = ti;
      int a1 = (base + 32 * (2 * m2 + 1)) ^ (((2 * m2 + 1) & 7) << 2);
      cmul(xr[2 * m2 + 1], xi[2 * m2 + 1], w.z, w.w, tr, ti);
      sre[a1] = tr; sim[a1] = ti;
    }
  }
  __syncthreads();

  // ---- P3: radix-2 split + DFT16 + spectral mul + iDFT16 + inv radix-2 ----
  {
    const int k = t >> 1, par = t & 1;
    const int kx = k & 7;
    const float sgn = par ? -1.f : 1.f;
    float xr[16], xi[16];
#pragma unroll
    for (int c = 0; c < 4; ++c) {
      float4 lr = ((const float4*)sre)[8 * k + (c ^ kx)];
      float4 hr = ((const float4*)sre)[8 * k + ((c + 4) ^ kx)];
      float4 li = ((const float4*)sim)[8 * k + (c ^ kx)];
      float4 hi4 = ((const float4*)sim)[8 * k + ((c + 4) ^ kx)];
      float vr[4] = {lr.x + sgn * hr.x, lr.y + sgn * hr.y, lr.z + sgn * hr.z, lr.w + sgn * hr.w};
      float vi[4] = {li.x + sgn * hi4.x, li.y + sgn * hi4.y, li.z + sgn * hi4.z, li.w + sgn * hi4.w};
#pragma unroll
      for (int e = 0; e < 4; ++e) {
        const int j = 4 * c + e;
        const float twr = par ? W32C[j] : 1.f;
        const float tws = par ? W32S[j] : 0.f;
        cmul(vr[e], vi[e], twr, tws, xr[j], xi[j]);
      }
    }
    fft16_f(xr, xi);
    const float4* kf4 = (const float4*)(Kf + (size_t)h * NFFT * 2) + 8 * t;
#pragma unroll
    for (int c = 0; c < 8; ++c) {
      float4 kk = kf4[c];
      float tr, ti;
      cmul(xr[2 * c], xi[2 * c], kk.x, kk.y, tr, ti);
      xr[2 * c] = tr; xi[2 * c] = ti;
      cmul(xr[2 * c + 1], xi[2 * c + 1], kk.z, kk.w, tr, ti);
      xr[2 * c + 1] = tr; xi[2 * c + 1] = ti;
    }
    ifft16_f(xr, xi);
    // inverse radix-2 across the thread pair: even sends a~, odd sends conj(W)*b~
    float outr[16], outi[16];
#pragma unroll
    for (int j = 0; j < 16; ++j) {
      float pr, pi;
      if (par) cmul(xr[j], xi[j], W32C[j], -W32S[j], pr, pi);
      else { pr = xr[j]; pi = xi[j]; }
      float qr = __shfl_xor(pr, 1);
      float qi = __shfl_xor(pi, 1);
      outr[j] = par ? (qr - pr) : (pr + qr);
      outi[j] = par ? (qi - pi) : (pi + qi);
    }
#pragma unroll
    for (int c = 0; c < 4; ++c) {
      const int q = (4 * par + c) ^ kx;
      ((float4*)sre)[8 * k + q] = make_float4(outr[4 * c], outr[4 * c + 1], outr[4 * c + 2], outr[4 * c + 3]);
      ((float4*)sim)[8 * k + q] = make_float4(outi[4 * c], outi[4 * c + 1], outi[4 * c + 2], outi[4 * c + 3]);
    }
  }
  __syncthreads();

  // ---- P2' (conj twiddles) ----
  {
    const int jj = t & 31, gg = t >> 5;
    const int base = gg * 512 + jj;
    float yr[16], yi[16];
#pragma unroll
    for (int m2 = 0; m2 < 8; ++m2) {
      float4 w = tw2[m2 * 32 + jj];
      int a0 = (base + 32 * (2 * m2)) ^ (((2 * m2) & 7) << 2);
      cmul(sre[a0], sim[a0], w.x, -w.y, yr[2 * m2], yi[2 * m2]);
      int a1 = (base + 32 * (2 * m2 + 1)) ^ (((2 * m2 + 1) & 7) << 2);
      cmul(sre[a1], sim[a1], w.z, -w.w, yr[2 * m2 + 1], yi[2 * m2 + 1]);
    }
    ifft16_f(yr, yi);
#pragma unroll
    for (int m = 0; m < 16; ++m) {
      const int a = (base + 32 * m) ^ ((m & 7) << 2);
      sre[a] = yr[m]; sim[a] = yi[m];
    }
  }
  __syncthreads();

  // ---- P1' (conj twiddles) + epilogue (GELU -> bf16) ----
  {
    const int j = t;
    float yr[16], yi[16];
#pragma unroll
    for (int m2 = 0; m2 < 8; ++m2) {
      float4 w = tw1[m2 * 512 + j];
      cmul(sre[jx + 512 * (2 * m2)], sim[jx + 512 * (2 * m2)], w.x, -w.y,
           yr[2 * m2], yi[2 * m2]);
      cmul(sre[jx + 512 * (2 * m2 + 1)], sim[jx + 512 * (2 * m2 + 1)], w.z, -w.w,
           yr[2 * m2 + 1], yi[2 * m2 + 1]);
    }
    ifft16_f(yr, yi);
    __hip_bfloat16* g0 = g + ((size_t)(b0 * HH + h)) * LL;
    __hip_bfloat16* g1 = g + ((size_t)(b1 * HH + h)) * LL;
#pragma unroll
    for (int r = 0; r < 8; ++r) {
      g0[j + 512 * r] = __float2bfloat16(gelu_exact(yr[r]));
      g1[j + 512 * r] = __float2bfloat16(gelu_exact(yi[r]));
    }
  }
}

// -------- pass 2.5: transpose g[b][h][l] -> g2[b][l][h] (bf16) -------------
// LDS tile XOR-swizzled at int4 granularity (read was 16-way bank conflict).
__global__ __launch_bounds__(256) void transpose_kernel(
    const __hip_bfloat16* __restrict__ g, __hip_bfloat16* __restrict__ g2) {
  __shared__ unsigned short tile[64][72];
  const int lb = blockIdx.x;
  const int hb = blockIdx.y;
  const int b = blockIdx.z;
  const int l0 = lb * 64, h0 = hb * 64;
  const int tid = threadIdx.x;
  const int r = tid >> 3;        // 0..31
  const int gc = tid & 7;        // column group 0..7
  const int c = gc * 8;
  const unsigned short* gs = (const unsigned short*)g;
  unsigned short* g2s = (unsigned short*)g2;
  for (int it = 0; it < 2; ++it) {
    int rr = r + it * 32;
    int4 v = *(const int4*)(gs + ((size_t)(b * HH + h0 + rr)) * LL + l0 + c);
    *(int4*)&tile[rr][(gc ^ (rr >> 3)) << 3] = v;
  }
  __syncthreads();
  for (int it = 0; it < 2; ++it) {
    int rr = r + it * 32;
    const int pc = (rr & 7) | (((rr >> 3) ^ gc) << 3);
    unsigned short vals[8];
#pragma unroll
    for (int j = 0; j < 8; ++j) vals[j] = tile[c + j][pc];
    *(int4*)(g2s + ((size_t)(b * LL + l0 + rr)) * HH + h0 + c) = *(int4*)vals;
  }
}

// -------- pass 3: out[b][v][l] = silu(sum_h W[v][h]*g2[b][l][h] + bout[v]) -
__global__ __launch_bounds__(256, 4) void gemm_kernel(
    const __hip_bfloat16* __restrict__ Wb, const __hip_bfloat16* __restrict__ g2,
    const float* __restrict__ bout, float* __restrict__ out) {
  const int vt = blockIdx.x;  // 0..3
  const int lt = blockIdx.y;  // 0..31
  const int b = blockIdx.z;
  const int wave = threadIdx.x >> 6;
  const int ln = threadIdx.x & 63;
  const int wr = wave >> 1, wc = wave & 1;
  const int vbase = vt * 128 + wr * 64;
  const int lbase = lt * 128 + wc * 64;
  const int lane16 = ln & 15;
  const int quad = ln >> 4;

  floatx4 acc[4][4];
#pragma unroll
  for (int mi = 0; mi < 4; ++mi)
#pragma unroll
    for (int ni = 0; ni < 4; ++ni) acc[mi][ni] = (floatx4){0.f, 0.f, 0.f, 0.f};

  const unsigned short* A = (const unsigned short*)Wb;
  const unsigned short* Bm = (const unsigned short*)g2 + (size_t)b * LL * HH;

  for (int k0 = 0; k0 < HH; k0 += 32) {
    const int kk = k0 + quad * 8;
    short8 af[4], bf[4];
#pragma unroll
    for (int mi = 0; mi < 4; ++mi) {
      const int m = vbase + mi * 16 + lane16;
      af[mi] = *(const short8*)(A + (size_t)m * HH + kk);
    }
#pragma unroll
    for (int ni = 0; ni < 4; ++ni) {
      const int n = lbase + ni * 16 + lane16;
      bf[ni] = *(const short8*)(Bm + (size_t)n * HH + kk);
    }
#pragma unroll
    for (int mi = 0; mi < 4; ++mi)
#pragma unroll
      for (int ni = 0; ni < 4; ++ni)
        acc[mi][ni] = __builtin_amdgcn_mfma_f32_16x16x32_bf16(af[mi], bf[ni],
                                                              acc[mi][ni], 0, 0, 0);
  }

#pragma unroll
  for (int mi = 0; mi < 4; ++mi) {
#pragma unroll
    for (int r = 0; r < 4; ++r) {
      const int m = vbase + mi * 16 + quad * 4 + r;
      const float bias = bout[m];
#pragma unroll
      for (int ni = 0; ni < 4; ++ni) {
        const int n = lbase + ni * 16 + lane16;
        float y = acc[mi][ni][r] + bias;
        y = y / (1.f + __expf(-y));
        out[((size_t)(b * HH + m)) * LL + n] = y;
      }
    }
  }
}

extern "C" void kernel_launch(void* const* d_in, const int* in_sizes, int n_in,
                              void* d_out, int out_size, void* d_ws, size_t ws_size,
                              hipStream_t stream) {
  const float* u = (const float*)d_in[0];
  const float* kern = (const float*)d_in[1];
  const float* D = (const float*)d_in[2];
  const float* Wout = (const float*)d_in[3];
  const float* bout = (const float*)d_in[4];
  float* out = (float*)d_out;

  char* ws = (char*)d_ws;
  const size_t KF_BYTES = (size_t)HH * NFFT * sizeof(float2);
  const size_t G_BYTES = (size_t)BB * HH * LL * 2;
  float* Kf = (float*)ws;  // interleaved (re,im) pairs, scrambled order
  __hip_bfloat16* g = (__hip_bfloat16*)(ws + KF_BYTES);
  __hip_bfloat16* g2 = (__hip_bfloat16*)(ws + KF_BYTES + G_BYTES);
  __hip_bfloat16* Wb = (__hip_bfloat16*)(ws + KF_BYTES + 2 * G_BYTES);
  // Twiddle tables alias the head of the g2 region: all table reads (kf_kernel,
  // fftconv_kernel) complete before transpose_kernel writes g2 (same stream).
  float4* tw1 = (float4*)g2;          // 8*512*16 B = 64 KB
  float4* tw2 = tw1 + 8 * 512;        // 8*32*16 B = 4 KB

  twgen_kernel<<<dim3(8), dim3(512), 0, stream>>>(tw1, tw2);
  wconv_kernel<<<dim3((HH * HH) / 256), dim3(256), 0, stream>>>(Wout, Wb);
  kf_kernel<<<dim3(HH), dim3(512), 0, stream>>>(kern, D, Kf, tw1, tw2);
  fftconv_kernel<<<dim3(HH, BB / 2), dim3(512), 0, stream>>>(u, Kf, g, tw1, tw2);
  transpose_kernel<<<dim3(LL / 64, HH / 64, BB), dim3(256), 0, stream>>>(g, g2);
  gemm_kernel<<<dim3(HH / 128, LL / 128, BB), dim3(256), 0, stream>>>(Wb, g2, bout, out);
}

// Round 5
// 554.837 us; speedup vs baseline: 1.0613x; 1.0613x over previous
//
#include <hip/hip_runtime.h>
#include <hip/hip_bf16.h>
#include <math.h>

// Problem constants
#define BB 16
#define HH 512
#define LL 4096
#define NFFT 8192
#define LAM 0.001f

typedef __attribute__((ext_vector_type(8))) short short8;
typedef __attribute__((ext_vector_type(4))) float floatx4;

#define R2C 0.70710678118654752f

__device__ __forceinline__ void cmul(float ar, float ai, float br, float bi,
                                     float& cr, float& ci) {
  cr = ar * br - ai * bi;
  ci = ar * bi + ai * br;
}

// W16^e = exp(-2*pi*i*e/16)
constexpr float W16C[8] = {1.f, 0.92387953f, 0.70710678f, 0.38268343f, 0.f,
                           -0.38268343f, -0.70710678f, -0.92387953f};
constexpr float W16S[8] = {0.f, -0.38268343f, -0.70710678f, -0.92387953f, -1.f,
                           -0.92387953f, -0.70710678f, -0.38268343f};
// DIF radix-8 output slot order: slot s holds bin BR8[s]
constexpr int BR8[8] = {0, 4, 2, 6, 1, 5, 3, 7};
// W16 powers pre-permuted to slot order (k = BR8[s])
constexpr float W16CB[8] = {W16C[0], W16C[4], W16C[2], W16C[6],
                            W16C[1], W16C[5], W16C[3], W16C[7]};
constexpr float W16SB[8] = {W16S[0], W16S[4], W16S[2], W16S[6],
                            W16S[1], W16S[5], W16S[3], W16S[7]};

// LDS bank swizzle on complex index: XOR bits[0:3] with bits[4:7].
__device__ __forceinline__ int slotf(int a) { return a ^ ((a >> 4) & 15); }

// ---- 8-point DFT, DIF, output slots in BR8 bin order ----
__device__ __forceinline__ void fft8(float* r, float* i) {
  float t0r = r[0] + r[4], t0i = i[0] + i[4], u0r = r[0] - r[4], u0i = i[0] - i[4];
  float t1r = r[1] + r[5], t1i = i[1] + i[5], u1r = r[1] - r[5], u1i = i[1] - i[5];
  float t2r = r[2] + r[6], t2i = i[2] + i[6], u2r = r[2] - r[6], u2i = i[2] - i[6];
  float t3r = r[3] + r[7], t3i = i[3] + i[7], u3r = r[3] - r[7], u3i = i[3] - i[7];
  // twiddle u_k by w8^k: w8 = exp(-2pi i/8)
  float w1r = R2C * (u1r + u1i), w1i = R2C * (u1i - u1r);   // *(R2 - R2 i)
  float w2r = u2i, w2i = -u2r;                               // *(-i)
  float w3r = R2C * (u3i - u3r), w3i = -R2C * (u3r + u3i);   // *(-R2 - R2 i)
  // DFT4 on t (even bins)
  float p0r = t0r + t2r, p0i = t0i + t2i, q0r = t0r - t2r, q0i = t0i - t2i;
  float p1r = t1r + t3r, p1i = t1i + t3i, q1r = t1r - t3r, q1i = t1i - t3i;
  float s1r = q1i, s1i = -q1r;                               // *(-i)
  // DFT4 on u' (odd bins)
  float v0r = u0r + w2r, v0i = u0i + w2i, x0r = u0r - w2r, x0i = u0i - w2i;
  float v1r = w1r + w3r, v1i = w1i + w3i, x1r = w1r - w3r, x1i = w1i - w3i;
  float y1r = x1i, y1i = -x1r;                               // *(-i)
  r[0] = p0r + p1r; i[0] = p0i + p1i;   // bin 0
  r[1] = p0r - p1r; i[1] = p0i - p1i;   // bin 4
  r[2] = q0r + s1r; i[2] = q0i + s1i;   // bin 2
  r[3] = q0r - s1r; i[3] = q0i - s1i;   // bin 6
  r[4] = v0r + v1r; i[4] = v0i + v1i;   // bin 1
  r[5] = v0r - v1r; i[5] = v0i - v1i;   // bin 5
  r[6] = x0r + y1r; i[6] = x0i + y1i;   // bin 3
  r[7] = x0r - y1r; i[7] = x0i - y1i;   // bin 7
}

// ---- inverse: input slots in BR8 bin order, output natural, unnormalized x8
__device__ __forceinline__ void ifft8(float* r, float* i) {
  float p0r = r[0] + r[1], p0i = i[0] + i[1];
  float p1r = r[0] - r[1], p1i = i[0] - i[1];
  float q0r = r[2] + r[3], q0i = i[2] + i[3];
  float s1r = r[2] - r[3], s1i = i[2] - i[3];
  float v0r = r[4] + r[5], v0i = i[4] + i[5];
  float v1r = r[4] - r[5], v1i = i[4] - i[5];
  float x0r = r[6] + r[7], x0i = i[6] + i[7];
  float y1r = r[6] - r[7], y1i = i[6] - i[7];
  float q1r = -s1i, q1i = s1r;                               // *(+i)
  float x1r = -y1i, x1i = y1r;                               // *(+i)
  float t0r = p0r + q0r, t0i = p0i + q0i, t2r = p0r - q0r, t2i = p0i - q0i;
  float t1r = p1r + q1r, t1i = p1i + q1i, t3r = p1r - q1r, t3i = p1i - q1i;
  float a0r = v0r + x0r, a0i = v0i + x0i, a2r = v0r - x0r, a2i = v0i - x0i;
  float a1r = v1r + x1r, a1i = v1i + x1i, a3r = v1r - x1r, a3i = v1i - x1i;
  float u1r = R2C * (a1r - a1i), u1i = R2C * (a1r + a1i);    // *(R2 + R2 i)
  float u2r = -a2i, u2i = a2r;                               // *(+i)
  float u3r = -R2C * (a3r + a3i), u3i = R2C * (a3r - a3i);   // *(-R2 + R2 i)
  r[0] = t0r + a0r; i[0] = t0i + a0i;  r[4] = t0r - a0r; i[4] = t0i - a0i;
  r[1] = t1r + u1r; i[1] = t1i + u1i;  r[5] = t1r - u1r; i[5] = t1i - u1i;
  r[2] = t2r + u2r; i[2] = t2i + u2i;  r[6] = t2r - u2r; i[6] = t2i - u2i;
  r[3] = t3r + u3r; i[3] = t3i + u3i;  r[7] = t3r - u3r; i[7] = t3i - u3i;
}

__device__ __forceinline__ float gelu_exact(float y) {
  return 0.5f * y * (1.f + erff(y * 0.70710678118654752f));
}

// ---- generic middle radix-8 DIF phase (J = q-count = stride) ----
template <int LOGJ>
__device__ __forceinline__ void r8_fwd(float2* sb, int t, const float4* tw) {
  const int J = 1 << LOGJ;
  const int j = t & (J - 1);
  const int base = (t >> LOGJ) << (LOGJ + 3);
  float xr[8], xi[8];
#pragma unroll
  for (int s = 0; s < 8; ++s) {
    float2 v = sb[slotf(base + j + (s << LOGJ))];
    xr[s] = v.x; xi[s] = v.y;
  }
  fft8(xr, xi);
#pragma unroll
  for (int q = 0; q < 4; ++q) {
    float4 w = tw[(q << LOGJ) + j];
    float tr, ti;
    cmul(xr[2 * q], xi[2 * q], w.x, w.y, tr, ti);
    sb[slotf(base + (BR8[2 * q] << LOGJ) + j)] = make_float2(tr, ti);
    cmul(xr[2 * q + 1], xi[2 * q + 1], w.z, w.w, tr, ti);
    sb[slotf(base + (BR8[2 * q + 1] << LOGJ) + j)] = make_float2(tr, ti);
  }
}

template <int LOGJ>
__device__ __forceinline__ void r8_inv(float2* sb, int t, const float4* tw) {
  const int J = 1 << LOGJ;
  const int j = t & (J - 1);
  const int base = (t >> LOGJ) << (LOGJ + 3);
  float xr[8], xi[8];
#pragma unroll
  for (int q = 0; q < 4; ++q) {
    float4 w = tw[(q << LOGJ) + j];
    float2 v0 = sb[slotf(base + (BR8[2 * q] << LOGJ) + j)];
    cmul(v0.x, v0.y, w.x, -w.y, xr[2 * q], xi[2 * q]);
    float2 v1 = sb[slotf(base + (BR8[2 * q + 1] << LOGJ) + j)];
    cmul(v1.x, v1.y, w.z, -w.w, xr[2 * q + 1], xi[2 * q + 1]);
  }
  ifft8(xr, xi);
#pragma unroll
  for (int s = 0; s < 8; ++s)
    sb[slotf(base + j + (s << LOGJ))] = make_float2(xr[s], xi[s]);
}

// ---- phase 1 tail: fft8 + tw1 + scatter (input loaded by caller) ----
__device__ __forceinline__ void p1_scatter(float2* sb, int j, const float4* tw1,
                                           float* xr, float* xi) {
  fft8(xr, xi);
#pragma unroll
  for (int q = 0; q < 4; ++q) {
    float4 w = tw1[(q << 10) + j];
    float tr, ti;
    cmul(xr[2 * q], xi[2 * q], w.x, w.y, tr, ti);
    sb[slotf((BR8[2 * q] << 10) + j)] = make_float2(tr, ti);
    cmul(xr[2 * q + 1], xi[2 * q + 1], w.z, w.w, tr, ti);
    sb[slotf((BR8[2 * q + 1] << 10) + j)] = make_float2(tr, ti);
  }
}

// ---- phase 4: pairwise DFT16 (radix-2 + DFT8 + shfl combine) -> bins ----
__device__ __forceinline__ void p4_bins(float2* sb, int t, float* br_, float* bi_) {
  const int p = t >> 1, par = t & 1;
  const int a0 = (p << 4) + par;
  float xr[8], xi[8];
#pragma unroll
  for (int e = 0; e < 8; ++e) {
    float2 v = sb[slotf(a0 + 2 * e)];
    xr[e] = v.x; xi[e] = v.y;
  }
  fft8(xr, xi);
#pragma unroll
  for (int s = 0; s < 8; ++s) {
    float tr, ti;
    if (par) { cmul(xr[s], xi[s], W16CB[s], W16SB[s], tr, ti); }
    else { tr = xr[s]; ti = xi[s]; }
    float orr = __shfl_xor(tr, 1);
    float oii = __shfl_xor(ti, 1);
    br_[s] = par ? (orr - tr) : (tr + orr);   // par0: E+wO (bin k); par1: E-wO (bin k+8)
    bi_[s] = par ? (oii - ti) : (ti + oii);
  }
}

// ---- inverse phase 4: bins -> samples back to LDS ----
__device__ __forceinline__ void p4_inv(float2* sb, int t, float* br_, float* bi_) {
  const int p = t >> 1, par = t & 1;
  const int a0 = (p << 4) + par;
  float yr[8], yi[8];
#pragma unroll
  for (int s = 0; s < 8; ++s) {
    float orr = __shfl_xor(br_[s], 1);
    float oii = __shfl_xor(bi_[s], 1);
    float er = par ? (orr - br_[s]) : (br_[s] + orr);  // par0: A+B; par1: A-B
    float ei = par ? (oii - bi_[s]) : (bi_[s] + oii);
    if (par) { float tr, ti; cmul(er, ei, W16CB[s], -W16SB[s], tr, ti); er = tr; ei = ti; }
    yr[s] = er; yi[s] = ei;
  }
  ifft8(yr, yi);
#pragma unroll
  for (int e = 0; e < 8; ++e)
    sb[slotf(a0 + 2 * e)] = make_float2(yr[e], yi[e]);
}

// -------- pass -1: twiddle tables (bin order pre-permuted by BR8) ----------
__global__ __launch_bounds__(1024) void twgen_kernel(float4* __restrict__ tw1,
                                                     float4* __restrict__ tw2,
                                                     float4* __restrict__ tw3) {
  const int j = threadIdx.x;
#pragma unroll
  for (int q = 0; q < 4; ++q) {
    const int m0 = BR8[2 * q], m1 = BR8[2 * q + 1];
    float s0, c0, s1, c1;
    const float a1 = -6.283185307179586f / 8192.f;
    sincosf(a1 * (float)(j * m0), &s0, &c0);
    sincosf(a1 * (float)(j * m1), &s1, &c1);
    tw1[(q << 10) + j] = make_float4(c0, s0, c1, s1);
    if (j < 128) {
      const float a2 = -6.283185307179586f / 1024.f;
      sincosf(a2 * (float)(j * m0), &s0, &c0);
      sincosf(a2 * (float)(j * m1), &s1, &c1);
      tw2[(q << 7) + j] = make_float4(c0, s0, c1, s1);
    }
    if (j < 16) {
      const float a3 = -6.283185307179586f / 128.f;
      sincosf(a3 * (float)(j * m0), &s0, &c0);
      sincosf(a3 * (float)(j * m1), &s1, &c1);
      tw3[(q << 4) + j] = make_float4(c0, s0, c1, s1);
    }
  }
}

// -------- pass 0: Wout fp32 -> bf16 ----------------------------------------
__global__ void wconv_kernel(const float* __restrict__ W,
                             __hip_bfloat16* __restrict__ Wb) {
  int i = blockIdx.x * 256 + threadIdx.x;
  Wb[i] = __float2bfloat16(W[i]);
}

// -------- pass 1: squash + D-fold + scrambled spectrum (x 1/N) -------------
// 1024 threads, 8 pts/thread: one block = 16 waves fills the CU regardless of
// the 2-block co-residency cliff that capped the 512-thread version.
__global__ __launch_bounds__(1024)
void kf_kernel(const float* __restrict__ kern, const float* __restrict__ D,
               float* __restrict__ Kf, const float4* __restrict__ tw1,
               const float4* __restrict__ tw2, const float4* __restrict__ tw3) {
  __shared__ __align__(16) float2 sb[NFFT];
  const int t = threadIdx.x;
  const int h = blockIdx.x;
  const float* kr = kern + (size_t)h * LL;
  {
    float xr[8], xi[8];
#pragma unroll
    for (int s = 0; s < 4; ++s) {
      float kv = kr[t + (s << 10)];
      float a = fabsf(kv) - LAM;
      float sq = (a > 0.f) ? ((kv > 0.f) ? a : -a) : 0.f;
      xr[s] = sq * (1.f / 8192.f);
      xi[s] = 0.f;
    }
#pragma unroll
    for (int s = 4; s < 8; ++s) { xr[s] = 0.f; xi[s] = 0.f; }
    p1_scatter(sb, t, tw1, xr, xi);
  }
  __syncthreads();
  r8_fwd<7>(sb, t, tw2);
  __syncthreads();
  r8_fwd<4>(sb, t, tw3);
  __syncthreads();
  {
    float br_[8], bi_[8];
    p4_bins(sb, t, br_, bi_);
    const float dsc = D[h] * (1.f / 8192.f);  // skip-term fold: +D/N on every bin
    float4* out4 = (float4*)(Kf + (size_t)h * NFFT * 2) + (t << 2);
#pragma unroll
    for (int q = 0; q < 4; ++q)
      out4[q] = make_float4(br_[2 * q] + dsc, bi_[2 * q],
                            br_[2 * q + 1] + dsc, bi_[2 * q + 1]);
  }
}

// -------- pass 2: FFT conv (h, batch-pair) + GELU -> g bf16 ----------------
// grid = (HH, BB/2): id%8 = h%8 -> all 8 batch-pair blocks of one h share an
// XCD L2 for the Kf row.
__global__ __launch_bounds__(1024)
void fftconv_kernel(const float* __restrict__ u, const float* __restrict__ Kf,
                    __hip_bfloat16* __restrict__ g, const float4* __restrict__ tw1,
                    const float4* __restrict__ tw2, const float4* __restrict__ tw3) {
  __shared__ __align__(16) float2 sb[NFFT];
  const int t = threadIdx.x;
  const int h = blockIdx.x;
  const int p = blockIdx.y;
  const int b0 = 2 * p, b1 = 2 * p + 1;
  const float* u0 = u + ((size_t)(b0 * HH + h)) * LL;
  const float* u1 = u + ((size_t)(b1 * HH + h)) * LL;

  // Ph1: radix-8, q=1024, z = u0 + i*u1, zero-padded 4096->8192
  {
    float xr[8], xi[8];
#pragma unroll
    for (int s = 0; s < 4; ++s) {
      xr[s] = u0[t + (s << 10)];
      xi[s] = u1[t + (s << 10)];
    }
#pragma unroll
    for (int s = 4; s < 8; ++s) { xr[s] = 0.f; xi[s] = 0.f; }
    p1_scatter(sb, t, tw1, xr, xi);
  }
  __syncthreads();
  r8_fwd<7>(sb, t, tw2);
  __syncthreads();
  r8_fwd<4>(sb, t, tw3);
  __syncthreads();
  // Ph4 + spectral multiply + iPh4 (all in registers)
  {
    float br_[8], bi_[8];
    p4_bins(sb, t, br_, bi_);
    const float4* kf4 = (const float4*)(Kf + (size_t)h * NFFT * 2) + (t << 2);
#pragma unroll
    for (int q = 0; q < 4; ++q) {
      float4 kk = kf4[q];
      float tr, ti;
      cmul(br_[2 * q], bi_[2 * q], kk.x, kk.y, tr, ti);
      br_[2 * q] = tr; bi_[2 * q] = ti;
      cmul(br_[2 * q + 1], bi_[2 * q + 1], kk.z, kk.w, tr, ti);
      br_[2 * q + 1] = tr; bi_[2 * q + 1] = ti;
    }
    p4_inv(sb, t, br_, bi_);
  }
  __syncthreads();
  r8_inv<4>(sb, t, tw3);
  __syncthreads();
  r8_inv<7>(sb, t, tw2);
  __syncthreads();
  // iPh1 (conj tw1) + epilogue: keep n < 4096 (s < 4), GELU -> bf16
  {
    float xr[8], xi[8];
#pragma unroll
    for (int q = 0; q < 4; ++q) {
      float4 w = tw1[(q << 10) + t];
      float2 v0 = sb[slotf((BR8[2 * q] << 10) + t)];
      cmul(v0.x, v0.y, w.x, -w.y, xr[2 * q], xi[2 * q]);
      float2 v1 = sb[slotf((BR8[2 * q + 1] << 10) + t)];
      cmul(v1.x, v1.y, w.z, -w.w, xr[2 * q + 1], xi[2 * q + 1]);
    }
    ifft8(xr, xi);
    __hip_bfloat16* g0 = g + ((size_t)(b0 * HH + h)) * LL;
    __hip_bfloat16* g1 = g + ((size_t)(b1 * HH + h)) * LL;
#pragma unroll
    for (int s = 0; s < 4; ++s) {
      g0[t + (s << 10)] = __float2bfloat16(gelu_exact(xr[s]));
      g1[t + (s << 10)] = __float2bfloat16(gelu_exact(xi[s]));
    }
  }
}

// -------- pass 2.5: transpose g[b][h][l] -> g2[b][l][h] (bf16) -------------
__global__ __launch_bounds__(256) void transpose_kernel(
    const __hip_bfloat16* __restrict__ g, __hip_bfloat16* __restrict__ g2) {
  __shared__ unsigned short tile[64][72];
  const int lb = blockIdx.x;
  const int hb = blockIdx.y;
  const int b = blockIdx.z;
  const int l0 = lb * 64, h0 = hb * 64;
  const int tid = threadIdx.x;
  const int r = tid >> 3;
  const int gc = tid & 7;
  const int c = gc * 8;
  const unsigned short* gs = (const unsigned short*)g;
  unsigned short* g2s = (unsigned short*)g2;
  for (int it = 0; it < 2; ++it) {
    int rr = r + it * 32;
    int4 v = *(const int4*)(gs + ((size_t)(b * HH + h0 + rr)) * LL + l0 + c);
    *(int4*)&tile[rr][(gc ^ (rr >> 3)) << 3] = v;
  }
  __syncthreads();
  for (int it = 0; it < 2; ++it) {
    int rr = r + it * 32;
    const int pc = (rr & 7) | (((rr >> 3) ^ gc) << 3);
    unsigned short vals[8];
#pragma unroll
    for (int j = 0; j < 8; ++j) vals[j] = tile[c + j][pc];
    *(int4*)(g2s + ((size_t)(b * LL + l0 + rr)) * HH + h0 + c) = *(int4*)vals;
  }
}

// -------- pass 3: out[b][v][l] = silu(sum_h W[v][h]*g2[b][l][h] + bout[v]) -
__global__ __launch_bounds__(256, 4) void gemm_kernel(
    const __hip_bfloat16* __restrict__ Wb, const __hip_bfloat16* __restrict__ g2,
    const float* __restrict__ bout, float* __restrict__ out) {
  const int vt = blockIdx.x;
  const int lt = blockIdx.y;
  const int b = blockIdx.z;
  const int wave = threadIdx.x >> 6;
  const int ln = threadIdx.x & 63;
  const int wr = wave >> 1, wc = wave & 1;
  const int vbase = vt * 128 + wr * 64;
  const int lbase = lt * 128 + wc * 64;
  const int lane16 = ln & 15;
  const int quad = ln >> 4;

  floatx4 acc[4][4];
#pragma unroll
  for (int mi = 0; mi < 4; ++mi)
#pragma unroll
    for (int ni = 0; ni < 4; ++ni) acc[mi][ni] = (floatx4){0.f, 0.f, 0.f, 0.f};

  const unsigned short* A = (const unsigned short*)Wb;
  const unsigned short* Bm = (const unsigned short*)g2 + (size_t)b * LL * HH;

  for (int k0 = 0; k0 < HH; k0 += 32) {
    const int kk = k0 + quad * 8;
    short8 af[4], bf[4];
#pragma unroll
    for (int mi = 0; mi < 4; ++mi) {
      const int m = vbase + mi * 16 + lane16;
      af[mi] = *(const short8*)(A + (size_t)m * HH + kk);
    }
#pragma unroll
    for (int ni = 0; ni < 4; ++ni) {
      const int n = lbase + ni * 16 + lane16;
      bf[ni] = *(const short8*)(Bm + (size_t)n * HH + kk);
    }
#pragma unroll
    for (int mi = 0; mi < 4; ++mi)
#pragma unroll
      for (int ni = 0; ni < 4; ++ni)
        acc[mi][ni] = __builtin_amdgcn_mfma_f32_16x16x32_bf16(af[mi], bf[ni],
                                                              acc[mi][ni], 0, 0, 0);
  }

#pragma unroll
  for (int mi = 0; mi < 4; ++mi) {
#pragma unroll
    for (int r = 0; r < 4; ++r) {
      const int m = vbase + mi * 16 + quad * 4 + r;
      const float bias = bout[m];
#pragma unroll
      for (int ni = 0; ni < 4; ++ni) {
        const int n = lbase + ni * 16 + lane16;
        float y = acc[mi][ni][r] + bias;
        y = y / (1.f + __expf(-y));
        out[((size_t)(b * HH + m)) * LL + n] = y;
      }
    }
  }
}

extern "C" void kernel_launch(void* const* d_in, const int* in_sizes, int n_in,
                              void* d_out, int out_size, void* d_ws, size_t ws_size,
                              hipStream_t stream) {
  const float* u = (const float*)d_in[0];
  const float* kern = (const float*)d_in[1];
  const float* D = (const float*)d_in[2];
  const float* Wout = (const float*)d_in[3];
  const float* bout = (const float*)d_in[4];
  float* out = (float*)d_out;

  char* ws = (char*)d_ws;
  const size_t KF_BYTES = (size_t)HH * NFFT * sizeof(float2);
  const size_t G_BYTES = (size_t)BB * HH * LL * 2;
  float* Kf = (float*)ws;  // interleaved (re,im) pairs, scrambled order
  __hip_bfloat16* g = (__hip_bfloat16*)(ws + KF_BYTES);
  __hip_bfloat16* g2 = (__hip_bfloat16*)(ws + KF_BYTES + G_BYTES);
  __hip_bfloat16* Wb = (__hip_bfloat16*)(ws + KF_BYTES + 2 * G_BYTES);
  // Twiddle tables alias the head of g2: all table reads complete before
  // transpose_kernel writes g2 (same stream).
  float4* tw1 = (float4*)g2;          // 4*1024*16 B = 64 KB
  float4* tw2 = tw1 + 4 * 1024;       // 4*128*16 B = 8 KB
  float4* tw3 = tw2 + 4 * 128;        // 4*16*16 B = 1 KB

  twgen_kernel<<<dim3(1), dim3(1024), 0, stream>>>(tw1, tw2, tw3);
  wconv_kernel<<<dim3((HH * HH) / 256), dim3(256), 0, stream>>>(Wout, Wb);
  kf_kernel<<<dim3(HH), dim3(1024), 0, stream>>>(kern, D, Kf, tw1, tw2, tw3);
  fftconv_kernel<<<dim3(HH, BB / 2), dim3(1024), 0, stream>>>(u, Kf, g, tw1, tw2, tw3);
  transpose_kernel<<<dim3(LL / 64, HH / 64, BB), dim3(256), 0, stream>>>(g, g2);
  gemm_kernel<<<dim3(HH / 128, LL / 128, BB), dim3(256), 0, stream>>>(Wb, g2, bout, out);
}

// Round 6
// 537.751 us; speedup vs baseline: 1.0950x; 1.0318x over previous
//
#include <hip/hip_runtime.h>
#include <hip/hip_bf16.h>
#include <math.h>

// Problem constants
#define BB 16
#define HH 512
#define LL 4096
#define NFFT 8192
#define LAM 0.001f

typedef __attribute__((ext_vector_type(8))) short short8;
typedef __attribute__((ext_vector_type(4))) float floatx4;

#define R2C 0.70710678118654752f

__device__ __forceinline__ void cmul(float ar, float ai, float br, float bi,
                                     float& cr, float& ci) {
  cr = ar * br - ai * bi;
  ci = ar * bi + ai * br;
}

// W16^e = exp(-2*pi*i*e/16)
constexpr float W16C[8] = {1.f, 0.92387953f, 0.70710678f, 0.38268343f, 0.f,
                           -0.38268343f, -0.70710678f, -0.92387953f};
constexpr float W16S[8] = {0.f, -0.38268343f, -0.70710678f, -0.92387953f, -1.f,
                           -0.92387953f, -0.70710678f, -0.38268343f};
// DIF radix-8 output slot order: slot s holds bin BR8[s]
constexpr int BR8[8] = {0, 4, 2, 6, 1, 5, 3, 7};
// W16 powers pre-permuted to slot order (k = BR8[s])
constexpr float W16CB[8] = {W16C[0], W16C[4], W16C[2], W16C[6],
                            W16C[1], W16C[5], W16C[3], W16C[7]};
constexpr float W16SB[8] = {W16S[0], W16S[4], W16S[2], W16S[6],
                            W16S[1], W16S[5], W16S[3], W16S[7]};

// LDS bank swizzle on complex index: XOR bits[0:3] with bits[4:7].
__device__ __forceinline__ int slotf(int a) { return a ^ ((a >> 4) & 15); }

// ---- 8-point DFT, DIF, output slots in BR8 bin order ----
__device__ __forceinline__ void fft8(float* r, float* i) {
  float t0r = r[0] + r[4], t0i = i[0] + i[4], u0r = r[0] - r[4], u0i = i[0] - i[4];
  float t1r = r[1] + r[5], t1i = i[1] + i[5], u1r = r[1] - r[5], u1i = i[1] - i[5];
  float t2r = r[2] + r[6], t2i = i[2] + i[6], u2r = r[2] - r[6], u2i = i[2] - i[6];
  float t3r = r[3] + r[7], t3i = i[3] + i[7], u3r = r[3] - r[7], u3i = i[3] - i[7];
  float w1r = R2C * (u1r + u1i), w1i = R2C * (u1i - u1r);   // *(R2 - R2 i)
  float w2r = u2i, w2i = -u2r;                               // *(-i)
  float w3r = R2C * (u3i - u3r), w3i = -R2C * (u3r + u3i);   // *(-R2 - R2 i)
  float p0r = t0r + t2r, p0i = t0i + t2i, q0r = t0r - t2r, q0i = t0i - t2i;
  float p1r = t1r + t3r, p1i = t1i + t3i, q1r = t1r - t3r, q1i = t1i - t3i;
  float s1r = q1i, s1i = -q1r;                               // *(-i)
  float v0r = u0r + w2r, v0i = u0i + w2i, x0r = u0r - w2r, x0i = u0i - w2i;
  float v1r = w1r + w3r, v1i = w1i + w3i, x1r = w1r - w3r, x1i = w1i - w3i;
  float y1r = x1i, y1i = -x1r;                               // *(-i)
  r[0] = p0r + p1r; i[0] = p0i + p1i;   // bin 0
  r[1] = p0r - p1r; i[1] = p0i - p1i;   // bin 4
  r[2] = q0r + s1r; i[2] = q0i + s1i;   // bin 2
  r[3] = q0r - s1r; i[3] = q0i - s1i;   // bin 6
  r[4] = v0r + v1r; i[4] = v0i + v1i;   // bin 1
  r[5] = v0r - v1r; i[5] = v0i - v1i;   // bin 5
  r[6] = x0r + y1r; i[6] = x0i + y1i;   // bin 3
  r[7] = x0r - y1r; i[7] = x0i - y1i;   // bin 7
}

// ---- fft8 specialized for x[4..7] == 0 (zero-padded first stage) ----
// First butterfly level collapses: t_k = u_k = x_k. Inputs r[0..3], i[0..3].
__device__ __forceinline__ void fft8_pad4(float* r, float* i) {
  float x0r = r[0], x0i = i[0], x1r = r[1], x1i = i[1];
  float x2r = r[2], x2i = i[2], x3r = r[3], x3i = i[3];
  float w1r = R2C * (x1r + x1i), w1i = R2C * (x1i - x1r);   // *(R2 - R2 i)
  float w2r = x2i, w2i = -x2r;                               // *(-i)
  float w3r = R2C * (x3i - x3r), w3i = -R2C * (x3r + x3i);   // *(-R2 - R2 i)
  float p0r = x0r + x2r, p0i = x0i + x2i, q0r = x0r - x2r, q0i = x0i - x2i;
  float p1r = x1r + x3r, p1i = x1i + x3i, q1r = x1r - x3r, q1i = x1i - x3i;
  float s1r = q1i, s1i = -q1r;                               // *(-i)
  float v0r = x0r + w2r, v0i = x0i + w2i, m0r = x0r - w2r, m0i = x0i - w2i;
  float v1r = w1r + w3r, v1i = w1i + w3i, m1r = w1r - w3r, m1i = w1i - w3i;
  float y1r = m1i, y1i = -m1r;                               // *(-i)
  r[0] = p0r + p1r; i[0] = p0i + p1i;
  r[1] = p0r - p1r; i[1] = p0i - p1i;
  r[2] = q0r + s1r; i[2] = q0i + s1i;
  r[3] = q0r - s1r; i[3] = q0i - s1i;
  r[4] = v0r + v1r; i[4] = v0i + v1i;
  r[5] = v0r - v1r; i[5] = v0i - v1i;
  r[6] = m0r + y1r; i[6] = m0i + y1i;
  r[7] = m0r - y1r; i[7] = m0i - y1i;
}

// ---- inverse: input slots in BR8 bin order, output natural, unnormalized x8
__device__ __forceinline__ void ifft8(float* r, float* i) {
  float p0r = r[0] + r[1], p0i = i[0] + i[1];
  float p1r = r[0] - r[1], p1i = i[0] - i[1];
  float q0r = r[2] + r[3], q0i = i[2] + i[3];
  float s1r = r[2] - r[3], s1i = i[2] - i[3];
  float v0r = r[4] + r[5], v0i = i[4] + i[5];
  float v1r = r[4] - r[5], v1i = i[4] - i[5];
  float x0r = r[6] + r[7], x0i = i[6] + i[7];
  float y1r = r[6] - r[7], y1i = i[6] - i[7];
  float q1r = -s1i, q1i = s1r;                               // *(+i)
  float x1r = -y1i, x1i = y1r;                               // *(+i)
  float t0r = p0r + q0r, t0i = p0i + q0i, t2r = p0r - q0r, t2i = p0i - q0i;
  float t1r = p1r + q1r, t1i = p1i + q1i, t3r = p1r - q1r, t3i = p1i - q1i;
  float a0r = v0r + x0r, a0i = v0i + x0i, a2r = v0r - x0r, a2i = v0i - x0i;
  float a1r = v1r + x1r, a1i = v1i + x1i, a3r = v1r - x1r, a3i = v1i - x1i;
  float u1r = R2C * (a1r - a1i), u1i = R2C * (a1r + a1i);    // *(R2 + R2 i)
  float u2r = -a2i, u2i = a2r;                               // *(+i)
  float u3r = -R2C * (a3r + a3i), u3i = R2C * (a3r - a3i);   // *(-R2 + R2 i)
  r[0] = t0r + a0r; i[0] = t0i + a0i;  r[4] = t0r - a0r; i[4] = t0i - a0i;
  r[1] = t1r + u1r; i[1] = t1i + u1i;  r[5] = t1r - u1r; i[5] = t1i - u1i;
  r[2] = t2r + u2r; i[2] = t2i + u2i;  r[6] = t2r - u2r; i[6] = t2i - u2i;
  r[3] = t3r + u3r; i[3] = t3i + u3i;  r[7] = t3r - u3r; i[7] = t3i - u3i;
}

// ---- truncated inverse: only outputs 0..3 (4..7 are discarded padding) ----
__device__ __forceinline__ void ifft8_head4(float* r, float* i) {
  float p0r = r[0] + r[1], p0i = i[0] + i[1];
  float p1r = r[0] - r[1], p1i = i[0] - i[1];
  float q0r = r[2] + r[3], q0i = i[2] + i[3];
  float s1r = r[2] - r[3], s1i = i[2] - i[3];
  float v0r = r[4] + r[5], v0i = i[4] + i[5];
  float v1r = r[4] - r[5], v1i = i[4] - i[5];
  float x0r = r[6] + r[7], x0i = i[6] + i[7];
  float y1r = r[6] - r[7], y1i = i[6] - i[7];
  float q1r = -s1i, q1i = s1r;                               // *(+i)
  float x1r = -y1i, x1i = y1r;                               // *(+i)
  float t0r = p0r + q0r, t0i = p0i + q0i, t2r = p0r - q0r, t2i = p0i - q0i;
  float t1r = p1r + q1r, t1i = p1i + q1i, t3r = p1r - q1r, t3i = p1i - q1i;
  float a0r = v0r + x0r, a0i = v0i + x0i, a2r = v0r - x0r, a2i = v0i - x0i;
  float a1r = v1r + x1r, a1i = v1i + x1i, a3r = v1r - x1r, a3i = v1i - x1i;
  float u1r = R2C * (a1r - a1i), u1i = R2C * (a1r + a1i);    // *(R2 + R2 i)
  float u2r = -a2i, u2i = a2r;                               // *(+i)
  float u3r = -R2C * (a3r + a3i), u3i = R2C * (a3r - a3i);   // *(-R2 + R2 i)
  r[0] = t0r + a0r; i[0] = t0i + a0i;
  r[1] = t1r + u1r; i[1] = t1i + u1i;
  r[2] = t2r + u2r; i[2] = t2i + u2i;
  r[3] = t3r + u3r; i[3] = t3i + u3i;
}

__device__ __forceinline__ float gelu_exact(float y) {
  return 0.5f * y * (1.f + erff(y * 0.70710678118654752f));
}

// ---- generic middle radix-8 DIF phase (tw may live in LDS) ----
template <int LOGJ>
__device__ __forceinline__ void r8_fwd(float2* sb, int t, const float4* tw) {
  const int J = 1 << LOGJ;
  const int j = t & (J - 1);
  const int base = (t >> LOGJ) << (LOGJ + 3);
  float xr[8], xi[8];
#pragma unroll
  for (int s = 0; s < 8; ++s) {
    float2 v = sb[slotf(base + j + (s << LOGJ))];
    xr[s] = v.x; xi[s] = v.y;
  }
  fft8(xr, xi);
#pragma unroll
  for (int q = 0; q < 4; ++q) {
    float4 w = tw[(q << LOGJ) + j];
    float tr, ti;
    cmul(xr[2 * q], xi[2 * q], w.x, w.y, tr, ti);
    sb[slotf(base + (BR8[2 * q] << LOGJ) + j)] = make_float2(tr, ti);
    cmul(xr[2 * q + 1], xi[2 * q + 1], w.z, w.w, tr, ti);
    sb[slotf(base + (BR8[2 * q + 1] << LOGJ) + j)] = make_float2(tr, ti);
  }
}

template <int LOGJ>
__device__ __forceinline__ void r8_inv(float2* sb, int t, const float4* tw) {
  const int J = 1 << LOGJ;
  const int j = t & (J - 1);
  const int base = (t >> LOGJ) << (LOGJ + 3);
  float xr[8], xi[8];
#pragma unroll
  for (int q = 0; q < 4; ++q) {
    float4 w = tw[(q << LOGJ) + j];
    float2 v0 = sb[slotf(base + (BR8[2 * q] << LOGJ) + j)];
    cmul(v0.x, v0.y, w.x, -w.y, xr[2 * q], xi[2 * q]);
    float2 v1 = sb[slotf(base + (BR8[2 * q + 1] << LOGJ) + j)];
    cmul(v1.x, v1.y, w.z, -w.w, xr[2 * q + 1], xi[2 * q + 1]);
  }
  ifft8(xr, xi);
#pragma unroll
  for (int s = 0; s < 8; ++s)
    sb[slotf(base + j + (s << LOGJ))] = make_float2(xr[s], xi[s]);
}

// ---- phase 1 tail: tw1 + scatter (fft already done by caller) ----
__device__ __forceinline__ void p1_scatter(float2* sb, int j, const float4* tw1,
                                           float* xr, float* xi) {
#pragma unroll
  for (int q = 0; q < 4; ++q) {
    float4 w = tw1[(q << 10) + j];
    float tr, ti;
    cmul(xr[2 * q], xi[2 * q], w.x, w.y, tr, ti);
    sb[slotf((BR8[2 * q] << 10) + j)] = make_float2(tr, ti);
    cmul(xr[2 * q + 1], xi[2 * q + 1], w.z, w.w, tr, ti);
    sb[slotf((BR8[2 * q + 1] << 10) + j)] = make_float2(tr, ti);
  }
}

// ---- phase 4: pairwise DFT16 (radix-2 + DFT8 + shfl combine) -> bins ----
// Cluster-local: thread t touches only sb[128*(t>>4) .. +128), i.e. the same
// 16-consecutive-thread cluster as r8_fwd<4>/r8_inv<4> -> intra-wave, and
// per-wave DS ops are in-order, so NO barrier is needed on either side.
__device__ __forceinline__ void p4_bins(float2* sb, int t, float* br_, float* bi_) {
  const int p = t >> 1, par = t & 1;
  const int a0 = (p << 4) + par;
  float xr[8], xi[8];
#pragma unroll
  for (int e = 0; e < 8; ++e) {
    float2 v = sb[slotf(a0 + 2 * e)];
    xr[e] = v.x; xi[e] = v.y;
  }
  fft8(xr, xi);
#pragma unroll
  for (int s = 0; s < 8; ++s) {
    float tr, ti;
    if (par) { cmul(xr[s], xi[s], W16CB[s], W16SB[s], tr, ti); }
    else { tr = xr[s]; ti = xi[s]; }
    float orr = __shfl_xor(tr, 1);
    float oii = __shfl_xor(ti, 1);
    br_[s] = par ? (orr - tr) : (tr + orr);   // par0: E+wO (bin k); par1: E-wO (bin k+8)
    bi_[s] = par ? (oii - ti) : (ti + oii);
  }
}

// ---- inverse phase 4: bins -> samples back to LDS (cluster-local too) ----
__device__ __forceinline__ void p4_inv(float2* sb, int t, float* br_, float* bi_) {
  const int p = t >> 1, par = t & 1;
  const int a0 = (p << 4) + par;
  float yr[8], yi[8];
#pragma unroll
  for (int s = 0; s < 8; ++s) {
    float orr = __shfl_xor(br_[s], 1);
    float oii = __shfl_xor(bi_[s], 1);
    float er = par ? (orr - br_[s]) : (br_[s] + orr);  // par0: A+B; par1: A-B
    float ei = par ? (oii - bi_[s]) : (bi_[s] + oii);
    if (par) { float tr, ti; cmul(er, ei, W16CB[s], -W16SB[s], tr, ti); er = tr; ei = ti; }
    yr[s] = er; yi[s] = ei;
  }
  ifft8(yr, yi);
#pragma unroll
  for (int e = 0; e < 8; ++e)
    sb[slotf(a0 + 2 * e)] = make_float2(yr[e], yi[e]);
}

// -------- pass -1: twiddle tables (bin order pre-permuted by BR8) ----------
__global__ __launch_bounds__(1024) void twgen_kernel(float4* __restrict__ tw1,
                                                     float4* __restrict__ tw2,
                                                     float4* __restrict__ tw3) {
  const int j = threadIdx.x;
#pragma unroll
  for (int q = 0; q < 4; ++q) {
    const int m0 = BR8[2 * q], m1 = BR8[2 * q + 1];
    float s0, c0, s1, c1;
    const float a1 = -6.283185307179586f / 8192.f;
    sincosf(a1 * (float)(j * m0), &s0, &c0);
    sincosf(a1 * (float)(j * m1), &s1, &c1);
    tw1[(q << 10) + j] = make_float4(c0, s0, c1, s1);
    if (j < 128) {
      const float a2 = -6.283185307179586f / 1024.f;
      sincosf(a2 * (float)(j * m0), &s0, &c0);
      sincosf(a2 * (float)(j * m1), &s1, &c1);
      tw2[(q << 7) + j] = make_float4(c0, s0, c1, s1);
    }
    if (j < 16) {
      const float a3 = -6.283185307179586f / 128.f;
      sincosf(a3 * (float)(j * m0), &s0, &c0);
      sincosf(a3 * (float)(j * m1), &s1, &c1);
      tw3[(q << 4) + j] = make_float4(c0, s0, c1, s1);
    }
  }
}

// -------- pass 0: Wout fp32 -> bf16 ----------------------------------------
__global__ void wconv_kernel(const float* __restrict__ W,
                             __hip_bfloat16* __restrict__ Wb) {
  int i = blockIdx.x * 256 + threadIdx.x;
  Wb[i] = __float2bfloat16(W[i]);
}

// -------- pass 1: squash + D-fold + scrambled spectrum (x 1/N) -------------
__global__ __launch_bounds__(1024)
void kf_kernel(const float* __restrict__ kern, const float* __restrict__ D,
               float* __restrict__ Kf, const float4* __restrict__ tw1,
               const float4* __restrict__ tw2, const float4* __restrict__ tw3) {
  __shared__ __align__(16) float2 sb[NFFT];
  __shared__ __align__(16) float4 ltw2[512];
  __shared__ __align__(16) float4 ltw3[64];
  const int t = threadIdx.x;
  const int h = blockIdx.x;
  const float* kr = kern + (size_t)h * LL;
  // stage middle-phase twiddles into spare LDS (covered by the Ph1 barrier)
  if (t < 512) ltw2[t] = tw2[t];
  if (t < 64) ltw3[t] = tw3[t];
  {
    float xr[8], xi[8];
#pragma unroll
    for (int s = 0; s < 4; ++s) {
      float kv = kr[t + (s << 10)];
      float a = fabsf(kv) - LAM;
      float sq = (a > 0.f) ? ((kv > 0.f) ? a : -a) : 0.f;
      xr[s] = sq * (1.f / 8192.f);
      xi[s] = 0.f;
    }
    fft8_pad4(xr, xi);
    p1_scatter(sb, t, tw1, xr, xi);
  }
  __syncthreads();
  r8_fwd<7>(sb, t, ltw2);
  __syncthreads();
  r8_fwd<4>(sb, t, ltw3);
  // no barrier: phase-4 is cluster-local (same 16-thread group, same wave)
  {
    float br_[8], bi_[8];
    p4_bins(sb, t, br_, bi_);
    const float dsc = D[h] * (1.f / 8192.f);  // skip-term fold: +D/N on every bin
    float4* out4 = (float4*)(Kf + (size_t)h * NFFT * 2) + (t << 2);
#pragma unroll
    for (int q = 0; q < 4; ++q)
      out4[q] = make_float4(br_[2 * q] + dsc, bi_[2 * q],
                            br_[2 * q + 1] + dsc, bi_[2 * q + 1]);
  }
}

// -------- pass 2: FFT conv (h, batch-pair) + GELU -> g bf16 ----------------
// grid = (HH, BB/2): id%8 = h%8 -> all 8 batch-pair blocks of one h share an
// XCD L2 for the Kf row.
__global__ __launch_bounds__(1024)
void fftconv_kernel(const float* __restrict__ u, const float* __restrict__ Kf,
                    __hip_bfloat16* __restrict__ g, const float4* __restrict__ tw1,
                    const float4* __restrict__ tw2, const float4* __restrict__ tw3) {
  __shared__ __align__(16) float2 sb[NFFT];
  __shared__ __align__(16) float4 ltw2[512];
  __shared__ __align__(16) float4 ltw3[64];
  const int t = threadIdx.x;
  const int h = blockIdx.x;
  const int p = blockIdx.y;
  const int b0 = 2 * p, b1 = 2 * p + 1;
  const float* u0 = u + ((size_t)(b0 * HH + h)) * LL;
  const float* u1 = u + ((size_t)(b1 * HH + h)) * LL;

  if (t < 512) ltw2[t] = tw2[t];
  if (t < 64) ltw3[t] = tw3[t];

  // Ph1: radix-8, q=1024, z = u0 + i*u1, zero-padded 4096->8192
  {
    float xr[8], xi[8];
#pragma unroll
    for (int s = 0; s < 4; ++s) {
      xr[s] = u0[t + (s << 10)];
      xi[s] = u1[t + (s << 10)];
    }
    fft8_pad4(xr, xi);
    p1_scatter(sb, t, tw1, xr, xi);
  }
  __syncthreads();
  r8_fwd<7>(sb, t, ltw2);
  __syncthreads();
  r8_fwd<4>(sb, t, ltw3);
  // no barrier: Ph3 -> Ph4 is cluster-local (intra-wave, DS in-order)
  {
    float br_[8], bi_[8];
    p4_bins(sb, t, br_, bi_);
    const float4* kf4 = (const float4*)(Kf + (size_t)h * NFFT * 2) + (t << 2);
#pragma unroll
    for (int q = 0; q < 4; ++q) {
      float4 kk = kf4[q];
      float tr, ti;
      cmul(br_[2 * q], bi_[2 * q], kk.x, kk.y, tr, ti);
      br_[2 * q] = tr; bi_[2 * q] = ti;
      cmul(br_[2 * q + 1], bi_[2 * q + 1], kk.z, kk.w, tr, ti);
      br_[2 * q + 1] = tr; bi_[2 * q + 1] = ti;
    }
    p4_inv(sb, t, br_, bi_);
  }
  // no barrier: Ph4' -> Ph3' is cluster-local too
  r8_inv<4>(sb, t, ltw3);
  __syncthreads();
  r8_inv<7>(sb, t, ltw2);
  __syncthreads();
  // iPh1 (conj tw1) + epilogue: keep n < 4096 only, GELU -> bf16
  {
    float xr[8], xi[8];
#pragma unroll
    for (int q = 0; q < 4; ++q) {
      float4 w = tw1[(q << 10) + t];
      float2 v0 = sb[slotf((BR8[2 * q] << 10) + t)];
      cmul(v0.x, v0.y, w.x, -w.y, xr[2 * q], xi[2 * q]);
      float2 v1 = sb[slotf((BR8[2 * q + 1] << 10) + t)];
      cmul(v1.x, v1.y, w.z, -w.w, xr[2 * q + 1], xi[2 * q + 1]);
    }
    ifft8_head4(xr, xi);
    __hip_bfloat16* g0 = g + ((size_t)(b0 * HH + h)) * LL;
    __hip_bfloat16* g1 = g + ((size_t)(b1 * HH + h)) * LL;
#pragma unroll
    for (int s = 0; s < 4; ++s) {
      g0[t + (s << 10)] = __float2bfloat16(gelu_exact(xr[s]));
      g1[t + (s << 10)] = __float2bfloat16(gelu_exact(xi[s]));
    }
  }
}

// -------- pass 2.5: transpose g[b][h][l] -> g2[b][l][h] (bf16) -------------
__global__ __launch_bounds__(256) void transpose_kernel(
    const __hip_bfloat16* __restrict__ g, __hip_bfloat16* __restrict__ g2) {
  __shared__ unsigned short tile[64][72];
  const int lb = blockIdx.x;
  const int hb = blockIdx.y;
  const int b = blockIdx.z;
  const int l0 = lb * 64, h0 = hb * 64;
  const int tid = threadIdx.x;
  const int r = tid >> 3;
  const int gc = tid & 7;
  const int c = gc * 8;
  const unsigned short* gs = (const unsigned short*)g;
  unsigned short* g2s = (unsigned short*)g2;
  for (int it = 0; it < 2; ++it) {
    int rr = r + it * 32;
    int4 v = *(const int4*)(gs + ((size_t)(b * HH + h0 + rr)) * LL + l0 + c);
    *(int4*)&tile[rr][(gc ^ (rr >> 3)) << 3] = v;
  }
  __syncthreads();
  for (int it = 0; it < 2; ++it) {
    int rr = r + it * 32;
    const int pc = (rr & 7) | (((rr >> 3) ^ gc) << 3);
    unsigned short vals[8];
#pragma unroll
    for (int j = 0; j < 8; ++j) vals[j] = tile[c + j][pc];
    *(int4*)(g2s + ((size_t)(b * LL + l0 + rr)) * HH + h0 + c) = *(int4*)vals;
  }
}

// -------- pass 3: out[b][v][l] = silu(sum_h W[v][h]*g2[b][l][h] + bout[v]) -
__global__ __launch_bounds__(256, 4) void gemm_kernel(
    const __hip_bfloat16* __restrict__ Wb, const __hip_bfloat16* __restrict__ g2,
    const float* __restrict__ bout, float* __restrict__ out) {
  const int vt = blockIdx.x;
  const int lt = blockIdx.y;
  const int b = blockIdx.z;
  const int wave = threadIdx.x >> 6;
  const int ln = threadIdx.x & 63;
  const int wr = wave >> 1, wc = wave & 1;
  const int vbase = vt * 128 + wr * 64;
  const int lbase = lt * 128 + wc * 64;
  const int lane16 = ln & 15;
  const int quad = ln >> 4;

  floatx4 acc[4][4];
#pragma unroll
  for (int mi = 0; mi < 4; ++mi)
#pragma unroll
    for (int ni = 0; ni < 4; ++ni) acc[mi][ni] = (floatx4){0.f, 0.f, 0.f, 0.f};

  const unsigned short* A = (const unsigned short*)Wb;
  const unsigned short* Bm = (const unsigned short*)g2 + (size_t)b * LL * HH;

  for (int k0 = 0; k0 < HH; k0 += 32) {
    const int kk = k0 + quad * 8;
    short8 af[4], bf[4];
#pragma unroll
    for (int mi = 0; mi < 4; ++mi) {
      const int m = vbase + mi * 16 + lane16;
      af[mi] = *(const short8*)(A + (size_t)m * HH + kk);
    }
#pragma unroll
    for (int ni = 0; ni < 4; ++ni) {
      const int n = lbase + ni * 16 + lane16;
      bf[ni] = *(const short8*)(Bm + (size_t)n * HH + kk);
    }
#pragma unroll
    for (int mi = 0; mi < 4; ++mi)
#pragma unroll
      for (int ni = 0; ni < 4; ++ni)
        acc[mi][ni] = __builtin_amdgcn_mfma_f32_16x16x32_bf16(af[mi], bf[ni],
                                                              acc[mi][ni], 0, 0, 0);
  }

#pragma unroll
  for (int mi = 0; mi < 4; ++mi) {
#pragma unroll
    for (int r = 0; r < 4; ++r) {
      const int m = vbase + mi * 16 + quad * 4 + r;
      const float bias = bout[m];
#pragma unroll
      for (int ni = 0; ni < 4; ++ni) {
        const int n = lbase + ni * 16 + lane16;
        float y = acc[mi][ni][r] + bias;
        y = y / (1.f + __expf(-y));
        out[((size_t)(b * HH + m)) * LL + n] = y;
      }
    }
  }
}

extern "C" void kernel_launch(void* const* d_in, const int* in_sizes, int n_in,
                              void* d_out, int out_size, void* d_ws, size_t ws_size,
                              hipStream_t stream) {
  const float* u = (const float*)d_in[0];
  const float* kern = (const float*)d_in[1];
  const float* D = (const float*)d_in[2];
  const float* Wout = (const float*)d_in[3];
  const float* bout = (const float*)d_in[4];
  float* out = (float*)d_out;

  char* ws = (char*)d_ws;
  const size_t KF_BYTES = (size_t)HH * NFFT * sizeof(float2);
  const size_t G_BYTES = (size_t)BB * HH * LL * 2;
  float* Kf = (float*)ws;  // interleaved (re,im) pairs, scrambled order
  __hip_bfloat16* g = (__hip_bfloat16*)(ws + KF_BYTES);
  __hip_bfloat16* g2 = (__hip_bfloat16*)(ws + KF_BYTES + G_BYTES);
  __hip_bfloat16* Wb = (__hip_bfloat16*)(ws + KF_BYTES + 2 * G_BYTES);
  // Twiddle tables alias the head of g2: all table reads complete before
  // transpose_kernel writes g2 (same stream).
  float4* tw1 = (float4*)g2;          // 4*1024*16 B = 64 KB
  float4* tw2 = tw1 + 4 * 1024;       // 4*128*16 B = 8 KB
  float4* tw3 = tw2 + 4 * 128;        // 4*16*16 B = 1 KB

  twgen_kernel<<<dim3(1), dim3(1024), 0, stream>>>(tw1, tw2, tw3);
  wconv_kernel<<<dim3((HH * HH) / 256), dim3(256), 0, stream>>>(Wout, Wb);
  kf_kernel<<<dim3(HH), dim3(1024), 0, stream>>>(kern, D, Kf, tw1, tw2, tw3);
  fftconv_kernel<<<dim3(HH, BB / 2), dim3(1024), 0, stream>>>(u, Kf, g, tw1, tw2, tw3);
  transpose_kernel<<<dim3(LL / 64, HH / 64, BB), dim3(256), 0, stream>>>(g, g2);
  gemm_kernel<<<dim3(HH / 128, LL / 128, BB), dim3(256), 0, stream>>>(Wb, g2, bout, out);
}

// Round 7
// 531.390 us; speedup vs baseline: 1.1081x; 1.0120x over previous
//
#include <hip/hip_runtime.h>
#include <hip/hip_bf16.h>
#include <math.h>

// Problem constants
#define BB 16
#define HH 512
#define LL 4096
#define NFFT 8192
#define LAM 0.001f

typedef __attribute__((ext_vector_type(8))) short short8;
typedef __attribute__((ext_vector_type(4))) float floatx4;

#define R2C 0.70710678118654752f

__device__ __forceinline__ void cmul(float ar, float ai, float br, float bi,
                                     float& cr, float& ci) {
  cr = ar * br - ai * bi;
  ci = ar * bi + ai * br;
}

// W16^e = exp(-2*pi*i*e/16)
constexpr float W16C[8] = {1.f, 0.92387953f, 0.70710678f, 0.38268343f, 0.f,
                           -0.38268343f, -0.70710678f, -0.92387953f};
constexpr float W16S[8] = {0.f, -0.38268343f, -0.70710678f, -0.92387953f, -1.f,
                           -0.92387953f, -0.70710678f, -0.38268343f};
// DIF radix-8 output slot order: slot s holds bin BR8[s]
constexpr int BR8[8] = {0, 4, 2, 6, 1, 5, 3, 7};
// W16 powers pre-permuted to slot order (k = BR8[s])
constexpr float W16CB[8] = {W16C[0], W16C[4], W16C[2], W16C[6],
                            W16C[1], W16C[5], W16C[3], W16C[7]};
constexpr float W16SB[8] = {W16S[0], W16S[4], W16S[2], W16S[6],
                            W16S[1], W16S[5], W16S[3], W16S[7]};

// LDS bank swizzle on complex index: XOR bits[0:3] with bits[4:7].
__device__ __forceinline__ int slotf(int a) { return a ^ ((a >> 4) & 15); }

// ---- 8-point DFT, DIF, output slots in BR8 bin order ----
__device__ __forceinline__ void fft8(float* r, float* i) {
  float t0r = r[0] + r[4], t0i = i[0] + i[4], u0r = r[0] - r[4], u0i = i[0] - i[4];
  float t1r = r[1] + r[5], t1i = i[1] + i[5], u1r = r[1] - r[5], u1i = i[1] - i[5];
  float t2r = r[2] + r[6], t2i = i[2] + i[6], u2r = r[2] - r[6], u2i = i[2] - i[6];
  float t3r = r[3] + r[7], t3i = i[3] + i[7], u3r = r[3] - r[7], u3i = i[3] - i[7];
  float w1r = R2C * (u1r + u1i), w1i = R2C * (u1i - u1r);   // *(R2 - R2 i)
  float w2r = u2i, w2i = -u2r;                               // *(-i)
  float w3r = R2C * (u3i - u3r), w3i = -R2C * (u3r + u3i);   // *(-R2 - R2 i)
  float p0r = t0r + t2r, p0i = t0i + t2i, q0r = t0r - t2r, q0i = t0i - t2i;
  float p1r = t1r + t3r, p1i = t1i + t3i, q1r = t1r - t3r, q1i = t1i - t3i;
  float s1r = q1i, s1i = -q1r;                               // *(-i)
  float v0r = u0r + w2r, v0i = u0i + w2i, x0r = u0r - w2r, x0i = u0i - w2i;
  float v1r = w1r + w3r, v1i = w1i + w3i, x1r = w1r - w3r, x1i = w1i - w3i;
  float y1r = x1i, y1i = -x1r;                               // *(-i)
  r[0] = p0r + p1r; i[0] = p0i + p1i;   // bin 0
  r[1] = p0r - p1r; i[1] = p0i - p1i;   // bin 4
  r[2] = q0r + s1r; i[2] = q0i + s1i;   // bin 2
  r[3] = q0r - s1r; i[3] = q0i - s1i;   // bin 6
  r[4] = v0r + v1r; i[4] = v0i + v1i;   // bin 1
  r[5] = v0r - v1r; i[5] = v0i - v1i;   // bin 5
  r[6] = x0r + y1r; i[6] = x0i + y1i;   // bin 3
  r[7] = x0r - y1r; i[7] = x0i - y1i;   // bin 7
}

// ---- fft8 specialized for x[4..7] == 0 (zero-padded first stage) ----
__device__ __forceinline__ void fft8_pad4(float* r, float* i) {
  float x0r = r[0], x0i = i[0], x1r = r[1], x1i = i[1];
  float x2r = r[2], x2i = i[2], x3r = r[3], x3i = i[3];
  float w1r = R2C * (x1r + x1i), w1i = R2C * (x1i - x1r);   // *(R2 - R2 i)
  float w2r = x2i, w2i = -x2r;                               // *(-i)
  float w3r = R2C * (x3i - x3r), w3i = -R2C * (x3r + x3i);   // *(-R2 - R2 i)
  float p0r = x0r + x2r, p0i = x0i + x2i, q0r = x0r - x2r, q0i = x0i - x2i;
  float p1r = x1r + x3r, p1i = x1i + x3i, q1r = x1r - x3r, q1i = x1i - x3i;
  float s1r = q1i, s1i = -q1r;                               // *(-i)
  float v0r = x0r + w2r, v0i = x0i + w2i, m0r = x0r - w2r, m0i = x0i - w2i;
  float v1r = w1r + w3r, v1i = w1i + w3i, m1r = w1r - w3r, m1i = w1i - w3i;
  float y1r = m1i, y1i = -m1r;                               // *(-i)
  r[0] = p0r + p1r; i[0] = p0i + p1i;
  r[1] = p0r - p1r; i[1] = p0i - p1i;
  r[2] = q0r + s1r; i[2] = q0i + s1i;
  r[3] = q0r - s1r; i[3] = q0i - s1i;
  r[4] = v0r + v1r; i[4] = v0i + v1i;
  r[5] = v0r - v1r; i[5] = v0i - v1i;
  r[6] = m0r + y1r; i[6] = m0i + y1i;
  r[7] = m0r - y1r; i[7] = m0i - y1i;
}

// ---- inverse: input slots in BR8 bin order, output natural, unnormalized x8
__device__ __forceinline__ void ifft8(float* r, float* i) {
  float p0r = r[0] + r[1], p0i = i[0] + i[1];
  float p1r = r[0] - r[1], p1i = i[0] - i[1];
  float q0r = r[2] + r[3], q0i = i[2] + i[3];
  float s1r = r[2] - r[3], s1i = i[2] - i[3];
  float v0r = r[4] + r[5], v0i = i[4] + i[5];
  float v1r = r[4] - r[5], v1i = i[4] - i[5];
  float x0r = r[6] + r[7], x0i = i[6] + i[7];
  float y1r = r[6] - r[7], y1i = i[6] - i[7];
  float q1r = -s1i, q1i = s1r;                               // *(+i)
  float x1r = -y1i, x1i = y1r;                               // *(+i)
  float t0r = p0r + q0r, t0i = p0i + q0i, t2r = p0r - q0r, t2i = p0i - q0i;
  float t1r = p1r + q1r, t1i = p1i + q1i, t3r = p1r - q1r, t3i = p1i - q1i;
  float a0r = v0r + x0r, a0i = v0i + x0i, a2r = v0r - x0r, a2i = v0i - x0i;
  float a1r = v1r + x1r, a1i = v1i + x1i, a3r = v1r - x1r, a3i = v1i - x1i;
  float u1r = R2C * (a1r - a1i), u1i = R2C * (a1r + a1i);    // *(R2 + R2 i)
  float u2r = -a2i, u2i = a2r;                               // *(+i)
  float u3r = -R2C * (a3r + a3i), u3i = R2C * (a3r - a3i);   // *(-R2 + R2 i)
  r[0] = t0r + a0r; i[0] = t0i + a0i;  r[4] = t0r - a0r; i[4] = t0i - a0i;
  r[1] = t1r + u1r; i[1] = t1i + u1i;  r[5] = t1r - u1r; i[5] = t1i - u1i;
  r[2] = t2r + u2r; i[2] = t2i + u2i;  r[6] = t2r - u2r; i[6] = t2i - u2i;
  r[3] = t3r + u3r; i[3] = t3i + u3i;  r[7] = t3r - u3r; i[7] = t3i - u3i;
}

// ---- truncated inverse: only outputs 0..3 (4..7 are discarded padding) ----
__device__ __forceinline__ void ifft8_head4(float* r, float* i) {
  float p0r = r[0] + r[1], p0i = i[0] + i[1];
  float p1r = r[0] - r[1], p1i = i[0] - i[1];
  float q0r = r[2] + r[3], q0i = i[2] + i[3];
  float s1r = r[2] - r[3], s1i = i[2] - i[3];
  float v0r = r[4] + r[5], v0i = i[4] + i[5];
  float v1r = r[4] - r[5], v1i = i[4] - i[5];
  float x0r = r[6] + r[7], x0i = i[6] + i[7];
  float y1r = r[6] - r[7], y1i = i[6] - i[7];
  float q1r = -s1i, q1i = s1r;                               // *(+i)
  float x1r = -y1i, x1i = y1r;                               // *(+i)
  float t0r = p0r + q0r, t0i = p0i + q0i, t2r = p0r - q0r, t2i = p0i - q0i;
  float t1r = p1r + q1r, t1i = p1i + q1i, t3r = p1r - q1r, t3i = p1i - q1i;
  float a0r = v0r + x0r, a0i = v0i + x0i, a2r = v0r - x0r, a2i = v0i - x0i;
  float a1r = v1r + x1r, a1i = v1i + x1i, a3r = v1r - x1r, a3i = v1i - x1i;
  float u1r = R2C * (a1r - a1i), u1i = R2C * (a1r + a1i);    // *(R2 + R2 i)
  float u2r = -a2i, u2i = a2r;                               // *(+i)
  float u3r = -R2C * (a3r + a3i), u3i = R2C * (a3r - a3i);   // *(-R2 + R2 i)
  r[0] = t0r + a0r; i[0] = t0i + a0i;
  r[1] = t1r + u1r; i[1] = t1i + u1i;
  r[2] = t2r + u2r; i[2] = t2i + u2i;
  r[3] = t3r + u3r; i[3] = t3i + u3i;
}

__device__ __forceinline__ float gelu_exact(float y) {
  return 0.5f * y * (1.f + erff(y * 0.70710678118654752f));
}

// ---- generic middle radix-8 DIF phase (tw may live in LDS) ----
template <int LOGJ>
__device__ __forceinline__ void r8_fwd(float2* sb, int t, const float4* tw) {
  const int J = 1 << LOGJ;
  const int j = t & (J - 1);
  const int base = (t >> LOGJ) << (LOGJ + 3);
  float xr[8], xi[8];
#pragma unroll
  for (int s = 0; s < 8; ++s) {
    float2 v = sb[slotf(base + j + (s << LOGJ))];
    xr[s] = v.x; xi[s] = v.y;
  }
  fft8(xr, xi);
#pragma unroll
  for (int q = 0; q < 4; ++q) {
    float4 w = tw[(q << LOGJ) + j];
    float tr, ti;
    cmul(xr[2 * q], xi[2 * q], w.x, w.y, tr, ti);
    sb[slotf(base + (BR8[2 * q] << LOGJ) + j)] = make_float2(tr, ti);
    cmul(xr[2 * q + 1], xi[2 * q + 1], w.z, w.w, tr, ti);
    sb[slotf(base + (BR8[2 * q + 1] << LOGJ) + j)] = make_float2(tr, ti);
  }
}

template <int LOGJ>
__device__ __forceinline__ void r8_inv(float2* sb, int t, const float4* tw) {
  const int J = 1 << LOGJ;
  const int j = t & (J - 1);
  const int base = (t >> LOGJ) << (LOGJ + 3);
  float xr[8], xi[8];
#pragma unroll
  for (int q = 0; q < 4; ++q) {
    float4 w = tw[(q << LOGJ) + j];
    float2 v0 = sb[slotf(base + (BR8[2 * q] << LOGJ) + j)];
    cmul(v0.x, v0.y, w.x, -w.y, xr[2 * q], xi[2 * q]);
    float2 v1 = sb[slotf(base + (BR8[2 * q + 1] << LOGJ) + j)];
    cmul(v1.x, v1.y, w.z, -w.w, xr[2 * q + 1], xi[2 * q + 1]);
  }
  ifft8(xr, xi);
#pragma unroll
  for (int s = 0; s < 8; ++s)
    sb[slotf(base + j + (s << LOGJ))] = make_float2(xr[s], xi[s]);
}

// ---- phase 1 tail: tw1 + scatter (fft already done by caller) ----
__device__ __forceinline__ void p1_scatter(float2* sb, int j, const float4* tw1,
                                           float* xr, float* xi) {
#pragma unroll
  for (int q = 0; q < 4; ++q) {
    float4 w = tw1[(q << 10) + j];
    float tr, ti;
    cmul(xr[2 * q], xi[2 * q], w.x, w.y, tr, ti);
    sb[slotf((BR8[2 * q] << 10) + j)] = make_float2(tr, ti);
    cmul(xr[2 * q + 1], xi[2 * q + 1], w.z, w.w, tr, ti);
    sb[slotf((BR8[2 * q + 1] << 10) + j)] = make_float2(tr, ti);
  }
}

// ---- phase 4: pairwise DFT16 (radix-2 + DFT8 + shfl combine) -> bins ----
// Cluster-local (16 consecutive threads, same wave): no barrier needed.
__device__ __forceinline__ void p4_bins(float2* sb, int t, float* br_, float* bi_) {
  const int p = t >> 1, par = t & 1;
  const int a0 = (p << 4) + par;
  float xr[8], xi[8];
#pragma unroll
  for (int e = 0; e < 8; ++e) {
    float2 v = sb[slotf(a0 + 2 * e)];
    xr[e] = v.x; xi[e] = v.y;
  }
  fft8(xr, xi);
#pragma unroll
  for (int s = 0; s < 8; ++s) {
    float tr, ti;
    if (par) { cmul(xr[s], xi[s], W16CB[s], W16SB[s], tr, ti); }
    else { tr = xr[s]; ti = xi[s]; }
    float orr = __shfl_xor(tr, 1);
    float oii = __shfl_xor(ti, 1);
    br_[s] = par ? (orr - tr) : (tr + orr);
    bi_[s] = par ? (oii - ti) : (ti + oii);
  }
}

// ---- inverse phase 4: bins -> samples back to LDS (cluster-local too) ----
__device__ __forceinline__ void p4_inv(float2* sb, int t, float* br_, float* bi_) {
  const int p = t >> 1, par = t & 1;
  const int a0 = (p << 4) + par;
  float yr[8], yi[8];
#pragma unroll
  for (int s = 0; s < 8; ++s) {
    float orr = __shfl_xor(br_[s], 1);
    float oii = __shfl_xor(bi_[s], 1);
    float er = par ? (orr - br_[s]) : (br_[s] + orr);
    float ei = par ? (oii - bi_[s]) : (bi_[s] + oii);
    if (par) { float tr, ti; cmul(er, ei, W16CB[s], -W16SB[s], tr, ti); er = tr; ei = ti; }
    yr[s] = er; yi[s] = ei;
  }
  ifft8(yr, yi);
#pragma unroll
  for (int e = 0; e < 8; ++e)
    sb[slotf(a0 + 2 * e)] = make_float2(yr[e], yi[e]);
}

// -------- pass -1: twiddle tables (bin order pre-permuted by BR8) ----------
__global__ __launch_bounds__(1024) void twgen_kernel(float4* __restrict__ tw1,
                                                     float4* __restrict__ tw2,
                                                     float4* __restrict__ tw3) {
  const int j = threadIdx.x;
#pragma unroll
  for (int q = 0; q < 4; ++q) {
    const int m0 = BR8[2 * q], m1 = BR8[2 * q + 1];
    float s0, c0, s1, c1;
    const float a1 = -6.283185307179586f / 8192.f;
    sincosf(a1 * (float)(j * m0), &s0, &c0);
    sincosf(a1 * (float)(j * m1), &s1, &c1);
    tw1[(q << 10) + j] = make_float4(c0, s0, c1, s1);
    if (j < 128) {
      const float a2 = -6.283185307179586f / 1024.f;
      sincosf(a2 * (float)(j * m0), &s0, &c0);
      sincosf(a2 * (float)(j * m1), &s1, &c1);
      tw2[(q << 7) + j] = make_float4(c0, s0, c1, s1);
    }
    if (j < 16) {
      const float a3 = -6.283185307179586f / 128.f;
      sincosf(a3 * (float)(j * m0), &s0, &c0);
      sincosf(a3 * (float)(j * m1), &s1, &c1);
      tw3[(q << 4) + j] = make_float4(c0, s0, c1, s1);
    }
  }
}

// -------- pass 0: Wout fp32 -> bf16 ----------------------------------------
__global__ void wconv_kernel(const float* __restrict__ W,
                             __hip_bfloat16* __restrict__ Wb) {
  int i = blockIdx.x * 256 + threadIdx.x;
  Wb[i] = __float2bfloat16(W[i]);
}

// -------- pass 1: squash + D-fold + scrambled spectrum (x 1/N) -------------
__global__ __launch_bounds__(1024)
void kf_kernel(const float* __restrict__ kern, const float* __restrict__ D,
               float* __restrict__ Kf, const float4* __restrict__ tw1,
               const float4* __restrict__ tw2, const float4* __restrict__ tw3) {
  __shared__ __align__(16) float2 sb[NFFT];
  __shared__ __align__(16) float4 ltw2[512];
  __shared__ __align__(16) float4 ltw3[64];
  const int t = threadIdx.x;
  const int h = blockIdx.x;
  const float* kr = kern + (size_t)h * LL;
  if (t < 512) ltw2[t] = tw2[t];
  if (t < 64) ltw3[t] = tw3[t];
  {
    float xr[8], xi[8];
#pragma unroll
    for (int s = 0; s < 4; ++s) {
      float kv = kr[t + (s << 10)];
      float a = fabsf(kv) - LAM;
      float sq = (a > 0.f) ? ((kv > 0.f) ? a : -a) : 0.f;
      xr[s] = sq * (1.f / 8192.f);
      xi[s] = 0.f;
    }
    fft8_pad4(xr, xi);
    p1_scatter(sb, t, tw1, xr, xi);
  }
  __syncthreads();
  r8_fwd<7>(sb, t, ltw2);
  __syncthreads();
  r8_fwd<4>(sb, t, ltw3);
  {
    float br_[8], bi_[8];
    p4_bins(sb, t, br_, bi_);
    const float dsc = D[h] * (1.f / 8192.f);  // skip-term fold: +D/N on every bin
    float4* out4 = (float4*)(Kf + (size_t)h * NFFT * 2) + (t << 2);
#pragma unroll
    for (int q = 0; q < 4; ++q)
      out4[q] = make_float4(br_[2 * q] + dsc, bi_[2 * q],
                            br_[2 * q + 1] + dsc, bi_[2 * q + 1]);
  }
}

// -------- pass 2: FFT conv (h, batch-pair) + GELU -> g bf16 ----------------
__global__ __launch_bounds__(1024)
void fftconv_kernel(const float* __restrict__ u, const float* __restrict__ Kf,
                    __hip_bfloat16* __restrict__ g, const float4* __restrict__ tw1,
                    const float4* __restrict__ tw2, const float4* __restrict__ tw3) {
  __shared__ __align__(16) float2 sb[NFFT];
  __shared__ __align__(16) float4 ltw2[512];
  __shared__ __align__(16) float4 ltw3[64];
  const int t = threadIdx.x;
  const int h = blockIdx.x;
  const int p = blockIdx.y;
  const int b0 = 2 * p, b1 = 2 * p + 1;
  const float* u0 = u + ((size_t)(b0 * HH + h)) * LL;
  const float* u1 = u + ((size_t)(b1 * HH + h)) * LL;

  if (t < 512) ltw2[t] = tw2[t];
  if (t < 64) ltw3[t] = tw3[t];

  {
    float xr[8], xi[8];
#pragma unroll
    for (int s = 0; s < 4; ++s) {
      xr[s] = u0[t + (s << 10)];
      xi[s] = u1[t + (s << 10)];
    }
    fft8_pad4(xr, xi);
    p1_scatter(sb, t, tw1, xr, xi);
  }
  __syncthreads();
  r8_fwd<7>(sb, t, ltw2);
  __syncthreads();
  r8_fwd<4>(sb, t, ltw3);
  {
    float br_[8], bi_[8];
    p4_bins(sb, t, br_, bi_);
    const float4* kf4 = (const float4*)(Kf + (size_t)h * NFFT * 2) + (t << 2);
#pragma unroll
    for (int q = 0; q < 4; ++q) {
      float4 kk = kf4[q];
      float tr, ti;
      cmul(br_[2 * q], bi_[2 * q], kk.x, kk.y, tr, ti);
      br_[2 * q] = tr; bi_[2 * q] = ti;
      cmul(br_[2 * q + 1], bi_[2 * q + 1], kk.z, kk.w, tr, ti);
      br_[2 * q + 1] = tr; bi_[2 * q + 1] = ti;
    }
    p4_inv(sb, t, br_, bi_);
  }
  r8_inv<4>(sb, t, ltw3);
  __syncthreads();
  r8_inv<7>(sb, t, ltw2);
  __syncthreads();
  {
    float xr[8], xi[8];
#pragma unroll
    for (int q = 0; q < 4; ++q) {
      float4 w = tw1[(q << 10) + t];
      float2 v0 = sb[slotf((BR8[2 * q] << 10) + t)];
      cmul(v0.x, v0.y, w.x, -w.y, xr[2 * q], xi[2 * q]);
      float2 v1 = sb[slotf((BR8[2 * q + 1] << 10) + t)];
      cmul(v1.x, v1.y, w.z, -w.w, xr[2 * q + 1], xi[2 * q + 1]);
    }
    ifft8_head4(xr, xi);
    __hip_bfloat16* g0 = g + ((size_t)(b0 * HH + h)) * LL;
    __hip_bfloat16* g1 = g + ((size_t)(b1 * HH + h)) * LL;
#pragma unroll
    for (int s = 0; s < 4; ++s) {
      g0[t + (s << 10)] = __float2bfloat16(gelu_exact(xr[s]));
      g1[t + (s << 10)] = __float2bfloat16(gelu_exact(xi[s]));
    }
  }
}

// -------- pass 3 (FUSED transpose+GEMM):
// out[b][v][l] = silu(sum_h W[v][h]*g[b][h][l] + bout[v])
// B-operand staged through LDS with an in-staging transpose: global reads of
// g are coalesced rows [h][l-contiguous 16B]; LDS tile is [l][h] (pad 40 u16
// keeps ds_read_b128 16B-aligned, banks spread). Double-buffered, 1 barrier
// per k-step. Grid is 1-D with XCD-chunked work mapping so the 4 vt-blocks
// sharing a B-tile live on the SAME XCD L2.
#define BKP 40
__global__ __launch_bounds__(256, 4) void gemm_kernel(
    const __hip_bfloat16* __restrict__ Wb, const __hip_bfloat16* __restrict__ g,
    const float* __restrict__ bout, float* __restrict__ out) {
  __shared__ unsigned short bt[2][128][BKP];
  // XCD-chunked decode: 2048 work units, 8 XCDs x 256-unit chunks.
  const int id = blockIdx.x;
  const int w = (id & 7) * 256 + (id >> 3);
  const int vt = w & 3;          // fastest within chunk -> same-XCD B-tile share
  const int lt = (w >> 2) & 31;
  const int b = w >> 7;
  const int tid = threadIdx.x;
  const int wave = tid >> 6;
  const int ln = tid & 63;
  const int wr = wave >> 1, wc = wave & 1;
  const int vbase = vt * 128 + wr * 64;
  const int lbase0 = lt * 128;
  const int lane16 = ln & 15;
  const int quad = ln >> 4;

  floatx4 acc[4][4];
#pragma unroll
  for (int mi = 0; mi < 4; ++mi)
#pragma unroll
    for (int ni = 0; ni < 4; ++ni) acc[mi][ni] = (floatx4){0.f, 0.f, 0.f, 0.f};

  const unsigned short* A = (const unsigned short*)Wb;
  const unsigned short* gb = (const unsigned short*)g + (size_t)b * HH * LL;

  // staging: 32 h-rows x 128 l, 512 units of 8 elems; unit = (h_off, l_off)
  // global: row h = k0+h_off, cols lbase0+l_off..+8 (16B) -> LDS [l][h]
#define STAGE_B(BUF, K0)                                                       \
  {                                                                            \
    _Pragma("unroll") for (int it = 0; it < 2; ++it) {                         \
      const int uu = tid + it * 256;                                           \
      const int ho = uu >> 4;                                                  \
      const int lo = (uu & 15) * 8;                                            \
      int4 v = *(const int4*)(gb + (size_t)((K0) + ho) * LL + lbase0 + lo);    \
      unsigned short vs[8];                                                    \
      *(int4*)vs = v;                                                          \
      _Pragma("unroll") for (int e = 0; e < 8; ++e) bt[BUF][lo + e][ho] = vs[e]; \
    }                                                                          \
  }

  STAGE_B(0, 0);
  __syncthreads();

  for (int s = 0; s < 16; ++s) {
    const int cur = s & 1;
    if (s < 15) STAGE_B(cur ^ 1, (s + 1) * 32);
    const int kk = quad * 8;
    short8 af[4], bf[4];
#pragma unroll
    for (int mi = 0; mi < 4; ++mi) {
      const int m = vbase + mi * 16 + lane16;
      af[mi] = *(const short8*)(A + (size_t)m * HH + s * 32 + kk);
    }
#pragma unroll
    for (int ni = 0; ni < 4; ++ni) {
      const int nloc = wc * 64 + ni * 16 + lane16;
      bf[ni] = *(const short8*)(&bt[cur][nloc][kk]);
    }
#pragma unroll
    for (int mi = 0; mi < 4; ++mi)
#pragma unroll
      for (int ni = 0; ni < 4; ++ni)
        acc[mi][ni] = __builtin_amdgcn_mfma_f32_16x16x32_bf16(af[mi], bf[ni],
                                                              acc[mi][ni], 0, 0, 0);
    __syncthreads();
  }

#pragma unroll
  for (int mi = 0; mi < 4; ++mi) {
#pragma unroll
    for (int r = 0; r < 4; ++r) {
      const int m = vbase + mi * 16 + quad * 4 + r;
      const float bias = bout[m];
#pragma unroll
      for (int ni = 0; ni < 4; ++ni) {
        const int n = lbase0 + wc * 64 + ni * 16 + lane16;
        float y = acc[mi][ni][r] + bias;
        y = y / (1.f + __expf(-y));
        out[((size_t)(b * HH + m)) * LL + n] = y;
      }
    }
  }
#undef STAGE_B
}

extern "C" void kernel_launch(void* const* d_in, const int* in_sizes, int n_in,
                              void* d_out, int out_size, void* d_ws, size_t ws_size,
                              hipStream_t stream) {
  const float* u = (const float*)d_in[0];
  const float* kern = (const float*)d_in[1];
  const float* D = (const float*)d_in[2];
  const float* Wout = (const float*)d_in[3];
  const float* bout = (const float*)d_in[4];
  float* out = (float*)d_out;

  char* ws = (char*)d_ws;
  const size_t KF_BYTES = (size_t)HH * NFFT * sizeof(float2);
  const size_t G_BYTES = (size_t)BB * HH * LL * 2;
  float* Kf = (float*)ws;  // interleaved (re,im) pairs, scrambled order
  __hip_bfloat16* g = (__hip_bfloat16*)(ws + KF_BYTES);
  __hip_bfloat16* Wb = (__hip_bfloat16*)(ws + KF_BYTES + 2 * G_BYTES);
  // Twiddle tables live in the (now unused) former-g2 region.
  float4* tw1 = (float4*)(ws + KF_BYTES + G_BYTES);  // 4*1024*16 B = 64 KB
  float4* tw2 = tw1 + 4 * 1024;                      // 4*128*16 B = 8 KB
  float4* tw3 = tw2 + 4 * 128;                       // 4*16*16 B = 1 KB

  twgen_kernel<<<dim3(1), dim3(1024), 0, stream>>>(tw1, tw2, tw3);
  wconv_kernel<<<dim3((HH * HH) / 256), dim3(256), 0, stream>>>(Wout, Wb);
  kf_kernel<<<dim3(HH), dim3(1024), 0, stream>>>(kern, D, Kf, tw1, tw2, tw3);
  fftconv_kernel<<<dim3(HH, BB / 2), dim3(1024), 0, stream>>>(u, Kf, g, tw1, tw2, tw3);
  gemm_kernel<<<dim3(2048), dim3(256), 0, stream>>>(Wb, g, bout, out);
}

// Round 8
// 477.879 us; speedup vs baseline: 1.2322x; 1.1120x over previous
//
#include <hip/hip_runtime.h>
#include <hip/hip_bf16.h>
#include <math.h>

// Problem constants
#define BB 16
#define HH 512
#define LL 4096
#define NFFT 8192
#define LAM 0.001f

typedef __attribute__((ext_vector_type(8))) short short8;
typedef __attribute__((ext_vector_type(4))) float floatx4;

#define R2C 0.70710678118654752f

__device__ __forceinline__ void cmul(float ar, float ai, float br, float bi,
                                     float& cr, float& ci) {
  cr = ar * br - ai * bi;
  ci = ar * bi + ai * br;
}

// W16^e = exp(-2*pi*i*e/16)
constexpr float W16C[8] = {1.f, 0.92387953f, 0.70710678f, 0.38268343f, 0.f,
                           -0.38268343f, -0.70710678f, -0.92387953f};
constexpr float W16S[8] = {0.f, -0.38268343f, -0.70710678f, -0.92387953f, -1.f,
                           -0.92387953f, -0.70710678f, -0.38268343f};
// DIF radix-8 output slot order: slot s holds bin BR8[s]
constexpr int BR8[8] = {0, 4, 2, 6, 1, 5, 3, 7};
// W16 powers pre-permuted to slot order (k = BR8[s])
constexpr float W16CB[8] = {W16C[0], W16C[4], W16C[2], W16C[6],
                            W16C[1], W16C[5], W16C[3], W16C[7]};
constexpr float W16SB[8] = {W16S[0], W16S[4], W16S[2], W16S[6],
                            W16S[1], W16S[5], W16S[3], W16S[7]};

// LDS bank swizzle on complex index: XOR bits[0:3] with bits[4:7].
__device__ __forceinline__ int slotf(int a) { return a ^ ((a >> 4) & 15); }

// ---- 8-point DFT, DIF, output slots in BR8 bin order ----
__device__ __forceinline__ void fft8(float* r, float* i) {
  float t0r = r[0] + r[4], t0i = i[0] + i[4], u0r = r[0] - r[4], u0i = i[0] - i[4];
  float t1r = r[1] + r[5], t1i = i[1] + i[5], u1r = r[1] - r[5], u1i = i[1] - i[5];
  float t2r = r[2] + r[6], t2i = i[2] + i[6], u2r = r[2] - r[6], u2i = i[2] - i[6];
  float t3r = r[3] + r[7], t3i = i[3] + i[7], u3r = r[3] - r[7], u3i = i[3] - i[7];
  float w1r = R2C * (u1r + u1i), w1i = R2C * (u1i - u1r);   // *(R2 - R2 i)
  float w2r = u2i, w2i = -u2r;                               // *(-i)
  float w3r = R2C * (u3i - u3r), w3i = -R2C * (u3r + u3i);   // *(-R2 - R2 i)
  float p0r = t0r + t2r, p0i = t0i + t2i, q0r = t0r - t2r, q0i = t0i - t2i;
  float p1r = t1r + t3r, p1i = t1i + t3i, q1r = t1r - t3r, q1i = t1i - t3i;
  float s1r = q1i, s1i = -q1r;                               // *(-i)
  float v0r = u0r + w2r, v0i = u0i + w2i, x0r = u0r - w2r, x0i = u0i - w2i;
  float v1r = w1r + w3r, v1i = w1i + w3i, x1r = w1r - w3r, x1i = w1i - w3i;
  float y1r = x1i, y1i = -x1r;                               // *(-i)
  r[0] = p0r + p1r; i[0] = p0i + p1i;   // bin 0
  r[1] = p0r - p1r; i[1] = p0i - p1i;   // bin 4
  r[2] = q0r + s1r; i[2] = q0i + s1i;   // bin 2
  r[3] = q0r - s1r; i[3] = q0i - s1i;   // bin 6
  r[4] = v0r + v1r; i[4] = v0i + v1i;   // bin 1
  r[5] = v0r - v1r; i[5] = v0i - v1i;   // bin 5
  r[6] = x0r + y1r; i[6] = x0i + y1i;   // bin 3
  r[7] = x0r - y1r; i[7] = x0i - y1i;   // bin 7
}

// ---- fft8 specialized for x[4..7] == 0 (zero-padded first stage) ----
__device__ __forceinline__ void fft8_pad4(float* r, float* i) {
  float x0r = r[0], x0i = i[0], x1r = r[1], x1i = i[1];
  float x2r = r[2], x2i = i[2], x3r = r[3], x3i = i[3];
  float w1r = R2C * (x1r + x1i), w1i = R2C * (x1i - x1r);   // *(R2 - R2 i)
  float w2r = x2i, w2i = -x2r;                               // *(-i)
  float w3r = R2C * (x3i - x3r), w3i = -R2C * (x3r + x3i);   // *(-R2 - R2 i)
  float p0r = x0r + x2r, p0i = x0i + x2i, q0r = x0r - x2r, q0i = x0i - x2i;
  float p1r = x1r + x3r, p1i = x1i + x3i, q1r = x1r - x3r, q1i = x1i - x3i;
  float s1r = q1i, s1i = -q1r;                               // *(-i)
  float v0r = x0r + w2r, v0i = x0i + w2i, m0r = x0r - w2r, m0i = x0i - w2i;
  float v1r = w1r + w3r, v1i = w1i + w3i, m1r = w1r - w3r, m1i = w1i - w3i;
  float y1r = m1i, y1i = -m1r;                               // *(-i)
  r[0] = p0r + p1r; i[0] = p0i + p1i;
  r[1] = p0r - p1r; i[1] = p0i - p1i;
  r[2] = q0r + s1r; i[2] = q0i + s1i;
  r[3] = q0r - s1r; i[3] = q0i - s1i;
  r[4] = v0r + v1r; i[4] = v0i + v1i;
  r[5] = v0r - v1r; i[5] = v0i - v1i;
  r[6] = m0r + y1r; i[6] = m0i + y1i;
  r[7] = m0r - y1r; i[7] = m0i - y1i;
}

// ---- inverse: input slots in BR8 bin order, output natural, unnormalized x8
__device__ __forceinline__ void ifft8(float* r, float* i) {
  float p0r = r[0] + r[1], p0i = i[0] + i[1];
  float p1r = r[0] - r[1], p1i = i[0] - i[1];
  float q0r = r[2] + r[3], q0i = i[2] + i[3];
  float s1r = r[2] - r[3], s1i = i[2] - i[3];
  float v0r = r[4] + r[5], v0i = i[4] + i[5];
  float v1r = r[4] - r[5], v1i = i[4] - i[5];
  float x0r = r[6] + r[7], x0i = i[6] + i[7];
  float y1r = r[6] - r[7], y1i = i[6] - i[7];
  float q1r = -s1i, q1i = s1r;                               // *(+i)
  float x1r = -y1i, x1i = y1r;                               // *(+i)
  float t0r = p0r + q0r, t0i = p0i + q0i, t2r = p0r - q0r, t2i = p0i - q0i;
  float t1r = p1r + q1r, t1i = p1i + q1i, t3r = p1r - q1r, t3i = p1i - q1i;
  float a0r = v0r + x0r, a0i = v0i + x0i, a2r = v0r - x0r, a2i = v0i - x0i;
  float a1r = v1r + x1r, a1i = v1i + x1i, a3r = v1r - x1r, a3i = v1i - x1i;
  float u1r = R2C * (a1r - a1i), u1i = R2C * (a1r + a1i);    // *(R2 + R2 i)
  float u2r = -a2i, u2i = a2r;                               // *(+i)
  float u3r = -R2C * (a3r + a3i), u3i = R2C * (a3r - a3i);   // *(-R2 + R2 i)
  r[0] = t0r + a0r; i[0] = t0i + a0i;  r[4] = t0r - a0r; i[4] = t0i - a0i;
  r[1] = t1r + u1r; i[1] = t1i + u1i;  r[5] = t1r - u1r; i[5] = t1i - u1i;
  r[2] = t2r + u2r; i[2] = t2i + u2i;  r[6] = t2r - u2r; i[6] = t2i - u2i;
  r[3] = t3r + u3r; i[3] = t3i + u3i;  r[7] = t3r - u3r; i[7] = t3i - u3i;
}

// ---- truncated inverse: only outputs 0..3 (4..7 are discarded padding) ----
__device__ __forceinline__ void ifft8_head4(float* r, float* i) {
  float p0r = r[0] + r[1], p0i = i[0] + i[1];
  float p1r = r[0] - r[1], p1i = i[0] - i[1];
  float q0r = r[2] + r[3], q0i = i[2] + i[3];
  float s1r = r[2] - r[3], s1i = i[2] - i[3];
  float v0r = r[4] + r[5], v0i = i[4] + i[5];
  float v1r = r[4] - r[5], v1i = i[4] - i[5];
  float x0r = r[6] + r[7], x0i = i[6] + i[7];
  float y1r = r[6] - r[7], y1i = i[6] - i[7];
  float q1r = -s1i, q1i = s1r;                               // *(+i)
  float x1r = -y1i, x1i = y1r;                               // *(+i)
  float t0r = p0r + q0r, t0i = p0i + q0i, t2r = p0r - q0r, t2i = p0i - q0i;
  float t1r = p1r + q1r, t1i = p1i + q1i, t3r = p1r - q1r, t3i = p1i - q1i;
  float a0r = v0r + x0r, a0i = v0i + x0i, a2r = v0r - x0r, a2i = v0i - x0i;
  float a1r = v1r + x1r, a1i = v1i + x1i, a3r = v1r - x1r, a3i = v1i - x1i;
  float u1r = R2C * (a1r - a1i), u1i = R2C * (a1r + a1i);    // *(R2 + R2 i)
  float u2r = -a2i, u2i = a2r;                               // *(+i)
  float u3r = -R2C * (a3r + a3i), u3i = R2C * (a3r - a3i);   // *(-R2 + R2 i)
  r[0] = t0r + a0r; i[0] = t0i + a0i;
  r[1] = t1r + u1r; i[1] = t1i + u1i;
  r[2] = t2r + u2r; i[2] = t2i + u2i;
  r[3] = t3r + u3r; i[3] = t3i + u3i;
}

__device__ __forceinline__ float gelu_exact(float y) {
  return 0.5f * y * (1.f + erff(y * 0.70710678118654752f));
}

// ---- generic middle radix-8 DIF phase (tw may live in LDS) ----
template <int LOGJ>
__device__ __forceinline__ void r8_fwd(float2* sb, int t, const float4* tw) {
  const int J = 1 << LOGJ;
  const int j = t & (J - 1);
  const int base = (t >> LOGJ) << (LOGJ + 3);
  float xr[8], xi[8];
#pragma unroll
  for (int s = 0; s < 8; ++s) {
    float2 v = sb[slotf(base + j + (s << LOGJ))];
    xr[s] = v.x; xi[s] = v.y;
  }
  fft8(xr, xi);
#pragma unroll
  for (int q = 0; q < 4; ++q) {
    float4 w = tw[(q << LOGJ) + j];
    float tr, ti;
    cmul(xr[2 * q], xi[2 * q], w.x, w.y, tr, ti);
    sb[slotf(base + (BR8[2 * q] << LOGJ) + j)] = make_float2(tr, ti);
    cmul(xr[2 * q + 1], xi[2 * q + 1], w.z, w.w, tr, ti);
    sb[slotf(base + (BR8[2 * q + 1] << LOGJ) + j)] = make_float2(tr, ti);
  }
}

template <int LOGJ>
__device__ __forceinline__ void r8_inv(float2* sb, int t, const float4* tw) {
  const int J = 1 << LOGJ;
  const int j = t & (J - 1);
  const int base = (t >> LOGJ) << (LOGJ + 3);
  float xr[8], xi[8];
#pragma unroll
  for (int q = 0; q < 4; ++q) {
    float4 w = tw[(q << LOGJ) + j];
    float2 v0 = sb[slotf(base + (BR8[2 * q] << LOGJ) + j)];
    cmul(v0.x, v0.y, w.x, -w.y, xr[2 * q], xi[2 * q]);
    float2 v1 = sb[slotf(base + (BR8[2 * q + 1] << LOGJ) + j)];
    cmul(v1.x, v1.y, w.z, -w.w, xr[2 * q + 1], xi[2 * q + 1]);
  }
  ifft8(xr, xi);
#pragma unroll
  for (int s = 0; s < 8; ++s)
    sb[slotf(base + j + (s << LOGJ))] = make_float2(xr[s], xi[s]);
}

// ---- phase 1 tail: tw1 + scatter (fft already done by caller) ----
__device__ __forceinline__ void p1_scatter(float2* sb, int j, const float4* tw1,
                                           float* xr, float* xi) {
#pragma unroll
  for (int q = 0; q < 4; ++q) {
    float4 w = tw1[(q << 10) + j];
    float tr, ti;
    cmul(xr[2 * q], xi[2 * q], w.x, w.y, tr, ti);
    sb[slotf((BR8[2 * q] << 10) + j)] = make_float2(tr, ti);
    cmul(xr[2 * q + 1], xi[2 * q + 1], w.z, w.w, tr, ti);
    sb[slotf((BR8[2 * q + 1] << 10) + j)] = make_float2(tr, ti);
  }
}

// ---- phase 4: pairwise DFT16 (radix-2 + DFT8 + shfl combine) -> bins ----
// Cluster-local (16 consecutive threads, same wave): no barrier needed.
__device__ __forceinline__ void p4_bins(float2* sb, int t, float* br_, float* bi_) {
  const int p = t >> 1, par = t & 1;
  const int a0 = (p << 4) + par;
  float xr[8], xi[8];
#pragma unroll
  for (int e = 0; e < 8; ++e) {
    float2 v = sb[slotf(a0 + 2 * e)];
    xr[e] = v.x; xi[e] = v.y;
  }
  fft8(xr, xi);
#pragma unroll
  for (int s = 0; s < 8; ++s) {
    float tr, ti;
    if (par) { cmul(xr[s], xi[s], W16CB[s], W16SB[s], tr, ti); }
    else { tr = xr[s]; ti = xi[s]; }
    float orr = __shfl_xor(tr, 1);
    float oii = __shfl_xor(ti, 1);
    br_[s] = par ? (orr - tr) : (tr + orr);
    bi_[s] = par ? (oii - ti) : (ti + oii);
  }
}

// ---- inverse phase 4: bins -> samples back to LDS (cluster-local too) ----
__device__ __forceinline__ void p4_inv(float2* sb, int t, float* br_, float* bi_) {
  const int p = t >> 1, par = t & 1;
  const int a0 = (p << 4) + par;
  float yr[8], yi[8];
#pragma unroll
  for (int s = 0; s < 8; ++s) {
    float orr = __shfl_xor(br_[s], 1);
    float oii = __shfl_xor(bi_[s], 1);
    float er = par ? (orr - br_[s]) : (br_[s] + orr);
    float ei = par ? (oii - bi_[s]) : (bi_[s] + oii);
    if (par) { float tr, ti; cmul(er, ei, W16CB[s], -W16SB[s], tr, ti); er = tr; ei = ti; }
    yr[s] = er; yi[s] = ei;
  }
  ifft8(yr, yi);
#pragma unroll
  for (int e = 0; e < 8; ++e)
    sb[slotf(a0 + 2 * e)] = make_float2(yr[e], yi[e]);
}

// -------- pass -1: twiddle tables (bin order pre-permuted by BR8) ----------
__global__ __launch_bounds__(1024) void twgen_kernel(float4* __restrict__ tw1,
                                                     float4* __restrict__ tw2,
                                                     float4* __restrict__ tw3) {
  const int j = threadIdx.x;
#pragma unroll
  for (int q = 0; q < 4; ++q) {
    const int m0 = BR8[2 * q], m1 = BR8[2 * q + 1];
    float s0, c0, s1, c1;
    const float a1 = -6.283185307179586f / 8192.f;
    sincosf(a1 * (float)(j * m0), &s0, &c0);
    sincosf(a1 * (float)(j * m1), &s1, &c1);
    tw1[(q << 10) + j] = make_float4(c0, s0, c1, s1);
    if (j < 128) {
      const float a2 = -6.283185307179586f / 1024.f;
      sincosf(a2 * (float)(j * m0), &s0, &c0);
      sincosf(a2 * (float)(j * m1), &s1, &c1);
      tw2[(q << 7) + j] = make_float4(c0, s0, c1, s1);
    }
    if (j < 16) {
      const float a3 = -6.283185307179586f / 128.f;
      sincosf(a3 * (float)(j * m0), &s0, &c0);
      sincosf(a3 * (float)(j * m1), &s1, &c1);
      tw3[(q << 4) + j] = make_float4(c0, s0, c1, s1);
    }
  }
}

// -------- pass 0: Wout fp32 -> bf16 ----------------------------------------
__global__ void wconv_kernel(const float* __restrict__ W,
                             __hip_bfloat16* __restrict__ Wb) {
  int i = blockIdx.x * 256 + threadIdx.x;
  Wb[i] = __float2bfloat16(W[i]);
}

// -------- pass 1: squash + D-fold + scrambled spectrum (x 1/N) -------------
__global__ __launch_bounds__(1024)
void kf_kernel(const float* __restrict__ kern, const float* __restrict__ D,
               float* __restrict__ Kf, const float4* __restrict__ tw1,
               const float4* __restrict__ tw2, const float4* __restrict__ tw3) {
  __shared__ __align__(16) float2 sb[NFFT];
  __shared__ __align__(16) float4 ltw2[512];
  __shared__ __align__(16) float4 ltw3[64];
  const int t = threadIdx.x;
  const int h = blockIdx.x;
  const float* kr = kern + (size_t)h * LL;
  if (t < 512) ltw2[t] = tw2[t];
  if (t < 64) ltw3[t] = tw3[t];
  {
    float xr[8], xi[8];
#pragma unroll
    for (int s = 0; s < 4; ++s) {
      float kv = kr[t + (s << 10)];
      float a = fabsf(kv) - LAM;
      float sq = (a > 0.f) ? ((kv > 0.f) ? a : -a) : 0.f;
      xr[s] = sq * (1.f / 8192.f);
      xi[s] = 0.f;
    }
    fft8_pad4(xr, xi);
    p1_scatter(sb, t, tw1, xr, xi);
  }
  __syncthreads();
  r8_fwd<7>(sb, t, ltw2);
  __syncthreads();
  r8_fwd<4>(sb, t, ltw3);
  {
    float br_[8], bi_[8];
    p4_bins(sb, t, br_, bi_);
    const float dsc = D[h] * (1.f / 8192.f);  // skip-term fold: +D/N on every bin
    float4* out4 = (float4*)(Kf + (size_t)h * NFFT * 2) + (t << 2);
#pragma unroll
    for (int q = 0; q < 4; ++q)
      out4[q] = make_float4(br_[2 * q] + dsc, bi_[2 * q],
                            br_[2 * q + 1] + dsc, bi_[2 * q + 1]);
  }
}

// -------- pass 2: FFT conv (h, batch-pair) + GELU -> g bf16 ----------------
__global__ __launch_bounds__(1024)
void fftconv_kernel(const float* __restrict__ u, const float* __restrict__ Kf,
                    __hip_bfloat16* __restrict__ g, const float4* __restrict__ tw1,
                    const float4* __restrict__ tw2, const float4* __restrict__ tw3) {
  __shared__ __align__(16) float2 sb[NFFT];
  __shared__ __align__(16) float4 ltw2[512];
  __shared__ __align__(16) float4 ltw3[64];
  const int t = threadIdx.x;
  const int h = blockIdx.x;
  const int p = blockIdx.y;
  const int b0 = 2 * p, b1 = 2 * p + 1;
  const float* u0 = u + ((size_t)(b0 * HH + h)) * LL;
  const float* u1 = u + ((size_t)(b1 * HH + h)) * LL;

  if (t < 512) ltw2[t] = tw2[t];
  if (t < 64) ltw3[t] = tw3[t];

  {
    float xr[8], xi[8];
#pragma unroll
    for (int s = 0; s < 4; ++s) {
      xr[s] = u0[t + (s << 10)];
      xi[s] = u1[t + (s << 10)];
    }
    fft8_pad4(xr, xi);
    p1_scatter(sb, t, tw1, xr, xi);
  }
  __syncthreads();
  r8_fwd<7>(sb, t, ltw2);
  __syncthreads();
  r8_fwd<4>(sb, t, ltw3);
  {
    float br_[8], bi_[8];
    p4_bins(sb, t, br_, bi_);
    const float4* kf4 = (const float4*)(Kf + (size_t)h * NFFT * 2) + (t << 2);
#pragma unroll
    for (int q = 0; q < 4; ++q) {
      float4 kk = kf4[q];
      float tr, ti;
      cmul(br_[2 * q], bi_[2 * q], kk.x, kk.y, tr, ti);
      br_[2 * q] = tr; bi_[2 * q] = ti;
      cmul(br_[2 * q + 1], bi_[2 * q + 1], kk.z, kk.w, tr, ti);
      br_[2 * q + 1] = tr; bi_[2 * q + 1] = ti;
    }
    p4_inv(sb, t, br_, bi_);
  }
  r8_inv<4>(sb, t, ltw3);
  __syncthreads();
  r8_inv<7>(sb, t, ltw2);
  __syncthreads();
  {
    float xr[8], xi[8];
#pragma unroll
    for (int q = 0; q < 4; ++q) {
      float4 w = tw1[(q << 10) + t];
      float2 v0 = sb[slotf((BR8[2 * q] << 10) + t)];
      cmul(v0.x, v0.y, w.x, -w.y, xr[2 * q], xi[2 * q]);
      float2 v1 = sb[slotf((BR8[2 * q + 1] << 10) + t)];
      cmul(v1.x, v1.y, w.z, -w.w, xr[2 * q + 1], xi[2 * q + 1]);
    }
    ifft8_head4(xr, xi);
    __hip_bfloat16* g0 = g + ((size_t)(b0 * HH + h)) * LL;
    __hip_bfloat16* g1 = g + ((size_t)(b1 * HH + h)) * LL;
#pragma unroll
    for (int s = 0; s < 4; ++s) {
      g0[t + (s << 10)] = __float2bfloat16(gelu_exact(xr[s]));
      g1[t + (s << 10)] = __float2bfloat16(gelu_exact(xi[s]));
    }
  }
}

// -------- pass 3 (fused transpose+GEMM, LDS-staged both operands):
// out[b][v][l] = silu(sum_h W[v][h]*g[b][h][l] + bout[v])
// A-tile [128][40] u16 (pad 40 -> b128 writes/reads 2-way max).
// B-tile swizzled: element (l,h) at 16B-block blk = (l*4 + (h>>3)) ^ ((l>>3)&7),
// u16 offset h&7. Bijective; write banks spread 4-way (was 16-way with a
// linear pitch: l-stride 8 x any 16B-aligned pitch == 0 mod 32 banks);
// ds_read_b128 on reads stays 16B-aligned and ~2-way.
__global__ __launch_bounds__(256, 4) void gemm_kernel(
    const __hip_bfloat16* __restrict__ Wb, const __hip_bfloat16* __restrict__ g,
    const float* __restrict__ bout, float* __restrict__ out) {
  __shared__ unsigned short At[2][128][40];
  __shared__ unsigned short Bt[2][4096];
  // XCD-chunked decode: 2048 work units, 8 XCDs x 256-unit chunks; vt fastest
  // so the 4 blocks sharing a g-panel sit on the same XCD L2.
  const int id = blockIdx.x;
  const int w = (id & 7) * 256 + (id >> 3);
  const int vt = w & 3;
  const int lt = (w >> 2) & 31;
  const int b = w >> 7;
  const int tid = threadIdx.x;
  const int wave = tid >> 6;
  const int ln = tid & 63;
  const int wr = wave >> 1, wc = wave & 1;
  const int lane16 = ln & 15;
  const int quad = ln >> 4;
  const int lbase0 = lt * 128;

  // staging coords
  const int a_m = tid >> 2;            // rows a_m, a_m+64
  const int a_c = (tid & 3) * 8;       // k-offset within 32
  const int b_h = tid >> 4;            // rows b_h, b_h+16
  const int b_l = (tid & 15) * 8;      // 8 consecutive l

  const unsigned short* Ag = (const unsigned short*)Wb + (size_t)(vt * 128) * HH;
  const unsigned short* gb = (const unsigned short*)g + (size_t)b * HH * LL + lbase0;

  floatx4 acc[4][4];
#pragma unroll
  for (int mi = 0; mi < 4; ++mi)
#pragma unroll
    for (int ni = 0; ni < 4; ++ni) acc[mi][ni] = (floatx4){0.f, 0.f, 0.f, 0.f};

  int4 la0, la1, lb0, lb1;
#define GLOAD(K0)                                                         \
  la0 = *(const int4*)(Ag + (size_t)a_m * HH + (K0) + a_c);               \
  la1 = *(const int4*)(Ag + (size_t)(a_m + 64) * HH + (K0) + a_c);        \
  lb0 = *(const int4*)(gb + (size_t)((K0) + b_h) * LL + b_l);             \
  lb1 = *(const int4*)(gb + (size_t)((K0) + b_h + 16) * LL + b_l);
#define LWRITE(BUF)                                                       \
  *(int4*)&At[BUF][a_m][a_c] = la0;                                       \
  *(int4*)&At[BUF][a_m + 64][a_c] = la1;                                  \
  {                                                                       \
    unsigned short vs[8];                                                 \
    *(int4*)vs = lb0;                                                     \
    _Pragma("unroll") for (int e = 0; e < 8; ++e) {                       \
      const int l = b_l + e;                                              \
      const int blk = (l * 4 + (b_h >> 3)) ^ ((l >> 3) & 7);              \
      Bt[BUF][blk * 8 + (b_h & 7)] = vs[e];                               \
    }                                                                     \
    *(int4*)vs = lb1;                                                     \
    _Pragma("unroll") for (int e = 0; e < 8; ++e) {                       \
      const int l = b_l + e;                                              \
      const int h2 = b_h + 16;                                            \
      const int blk = (l * 4 + (h2 >> 3)) ^ ((l >> 3) & 7);               \
      Bt[BUF][blk * 8 + (h2 & 7)] = vs[e];                                \
    }                                                                     \
  }

  GLOAD(0);
  LWRITE(0);
  __syncthreads();

  const int kk = quad * 8;
  for (int s = 0; s < 16; ++s) {
    const int cur = s & 1;
    if (s < 15) { GLOAD((s + 1) * 32); }  // issue early: hide under MFMA
    short8 af[4], bf[4];
#pragma unroll
    for (int mi = 0; mi < 4; ++mi)
      af[mi] = *(const short8*)&At[cur][wr * 64 + mi * 16 + lane16][kk];
#pragma unroll
    for (int ni = 0; ni < 4; ++ni) {
      const int nloc = wc * 64 + ni * 16 + lane16;
      const int blk = (nloc * 4 + quad) ^ ((nloc >> 3) & 7);
      bf[ni] = *(const short8*)&Bt[cur][blk * 8];
    }
#pragma unroll
    for (int mi = 0; mi < 4; ++mi)
#pragma unroll
      for (int ni = 0; ni < 4; ++ni)
        acc[mi][ni] = __builtin_amdgcn_mfma_f32_16x16x32_bf16(af[mi], bf[ni],
                                                              acc[mi][ni], 0, 0, 0);
    if (s < 15) { LWRITE(cur ^ 1); }
    __syncthreads();
  }

#pragma unroll
  for (int mi = 0; mi < 4; ++mi) {
#pragma unroll
    for (int r = 0; r < 4; ++r) {
      const int m = vt * 128 + wr * 64 + mi * 16 + quad * 4 + r;
      const float bias = bout[m];
#pragma unroll
      for (int ni = 0; ni < 4; ++ni) {
        const int n = lbase0 + wc * 64 + ni * 16 + lane16;
        float y = acc[mi][ni][r] + bias;
        y = y / (1.f + __expf(-y));
        out[((size_t)(b * HH + m)) * LL + n] = y;
      }
    }
  }
#undef GLOAD
#undef LWRITE
}

extern "C" void kernel_launch(void* const* d_in, const int* in_sizes, int n_in,
                              void* d_out, int out_size, void* d_ws, size_t ws_size,
                              hipStream_t stream) {
  const float* u = (const float*)d_in[0];
  const float* kern = (const float*)d_in[1];
  const float* D = (const float*)d_in[2];
  const float* Wout = (const float*)d_in[3];
  const float* bout = (const float*)d_in[4];
  float* out = (float*)d_out;

  char* ws = (char*)d_ws;
  const size_t KF_BYTES = (size_t)HH * NFFT * sizeof(float2);
  const size_t G_BYTES = (size_t)BB * HH * LL * 2;
  float* Kf = (float*)ws;  // interleaved (re,im) pairs, scrambled order
  __hip_bfloat16* g = (__hip_bfloat16*)(ws + KF_BYTES);
  __hip_bfloat16* Wb = (__hip_bfloat16*)(ws + KF_BYTES + 2 * G_BYTES);
  float4* tw1 = (float4*)(ws + KF_BYTES + G_BYTES);  // 64 KB
  float4* tw2 = tw1 + 4 * 1024;                      // 8 KB
  float4* tw3 = tw2 + 4 * 128;                       // 1 KB

  twgen_kernel<<<dim3(1), dim3(1024), 0, stream>>>(tw1, tw2, tw3);
  wconv_kernel<<<dim3((HH * HH) / 256), dim3(256), 0, stream>>>(Wout, Wb);
  kf_kernel<<<dim3(HH), dim3(1024), 0, stream>>>(kern, D, Kf, tw1, tw2, tw3);
  fftconv_kernel<<<dim3(HH, BB / 2), dim3(1024), 0, stream>>>(u, Kf, g, tw1, tw2, tw3);
  gemm_kernel<<<dim3(2048), dim3(256), 0, stream>>>(Wb, g, bout, out);
}